// Round 1
// baseline (999.866 us; speedup 1.0000x reference)
//
#include <hip/hip_runtime.h>
#include <math.h>

#define NN   100000
#define NE   1600000
#define FIN  256
#define HID  64
#define NC   40
#define ETOT (NE + NN)

// ---------- degree / norm ----------
__global__ __launch_bounds__(256) void init_deg_k(float* __restrict__ deg) {
    int i = blockIdx.x * 256 + threadIdx.x;
    if (i < NN) deg[i] = 1.0f;               // self-loop weight
}

__global__ __launch_bounds__(256) void accum_deg_k(const int* __restrict__ dst,
                                                   const float* __restrict__ w,
                                                   float* __restrict__ deg) {
    int e = blockIdx.x * 256 + threadIdx.x;
    if (e < NE) atomicAdd(&deg[dst[e]], w[e]);
}

__global__ __launch_bounds__(256) void dinv_k(float* __restrict__ deg) {
    int i = blockIdx.x * 256 + threadIdx.x;
    if (i < NN) {
        float d = deg[i];
        deg[i] = (d > 0.f) ? rsqrtf(fmaxf(d, 1e-30f)) : 0.f;
    }
}

// ---------- layer-1 GEMM: h1 = x @ W1 ----------
__global__ __launch_bounds__(256) void gemm1_k(const float* __restrict__ x,
                                               const float* __restrict__ W1,
                                               float* __restrict__ h1) {
    __shared__ float xs[32 * FIN];           // 32 KB
    const int base_row = blockIdx.x * 32;    // NN % 32 == 0
    const float4* __restrict__ x4 = (const float4*)(x + (size_t)base_row * FIN);
    float4* xs4 = (float4*)xs;
#pragma unroll
    for (int i = 0; i < 8; ++i)
        xs4[threadIdx.x + i * 256] = x4[threadIdx.x + i * 256];
    __syncthreads();

    const int wave = threadIdx.x >> 6;
    const int lane = threadIdx.x & 63;       // output column
    const int r0 = wave * 8;                 // 8 rows per wave
    float acc[8];
#pragma unroll
    for (int j = 0; j < 8; ++j) acc[j] = 0.f;

    for (int kk = 0; kk < FIN; kk += 4) {
        float w0 = W1[(kk + 0) * HID + lane];
        float w1 = W1[(kk + 1) * HID + lane];
        float w2 = W1[(kk + 2) * HID + lane];
        float w3 = W1[(kk + 3) * HID + lane];
#pragma unroll
        for (int j = 0; j < 8; ++j) {
            float4 xq = *(const float4*)&xs[(r0 + j) * FIN + kk];  // broadcast b128
            acc[j] = fmaf(xq.x, w0, acc[j]);
            acc[j] = fmaf(xq.y, w1, acc[j]);
            acc[j] = fmaf(xq.z, w2, acc[j]);
            acc[j] = fmaf(xq.w, w3, acc[j]);
        }
    }
#pragma unroll
    for (int j = 0; j < 8; ++j)
        h1[(size_t)(base_row + r0 + j) * HID + lane] = acc[j];
}

// ---------- edge scatter, 64-wide ----------
__global__ __launch_bounds__(256) void scatter64_k(const int* __restrict__ src,
                                                   const int* __restrict__ dst,
                                                   const float* __restrict__ w,
                                                   const float* __restrict__ dinv,
                                                   const float* __restrict__ h,
                                                   float* __restrict__ agg) {
    const int e = blockIdx.x * 4 + (threadIdx.x >> 6);
    if (e >= ETOT) return;
    const int lane = threadIdx.x & 63;
    int s, d; float ww;
    if (e < NE) { s = src[e]; d = dst[e]; ww = w[e]; }
    else        { s = d = e - NE; ww = 1.0f; }
    const float nrm = dinv[s] * ww * dinv[d];
    atomicAdd(&agg[(size_t)d * HID + lane], h[(size_t)s * HID + lane] * nrm);
}

// ---------- layer-2 GEMM (fused relu(agg1+b1)): h2 = relu(agg1+b1) @ W2 ----------
__global__ __launch_bounds__(256) void gemm2_k(const float* __restrict__ agg1,
                                               const float* __restrict__ b1,
                                               const float* __restrict__ W2,
                                               float* __restrict__ h2) {
    __shared__ float w2s[HID * NC];
    __shared__ float b1s[HID];
    for (int i = threadIdx.x; i < HID * NC; i += 256) w2s[i] = W2[i];
    if (threadIdx.x < HID) b1s[threadIdx.x] = b1[threadIdx.x];
    __syncthreads();

    const int r = blockIdx.x * 256 + threadIdx.x;
    if (r >= NN) return;
    float acc[NC];
#pragma unroll
    for (int c = 0; c < NC; ++c) acc[c] = 0.f;

    const float4* row4 = (const float4*)(agg1 + (size_t)r * HID);
    for (int kk = 0; kk < HID; kk += 4) {
        float4 v = row4[kk >> 2];
        float xr0 = fmaxf(v.x + b1s[kk + 0], 0.f);
        float xr1 = fmaxf(v.y + b1s[kk + 1], 0.f);
        float xr2 = fmaxf(v.z + b1s[kk + 2], 0.f);
        float xr3 = fmaxf(v.w + b1s[kk + 3], 0.f);
#pragma unroll
        for (int c = 0; c < NC; ++c) {
            acc[c] = fmaf(xr0, w2s[(kk + 0) * NC + c], acc[c]);
            acc[c] = fmaf(xr1, w2s[(kk + 1) * NC + c], acc[c]);
            acc[c] = fmaf(xr2, w2s[(kk + 2) * NC + c], acc[c]);
            acc[c] = fmaf(xr3, w2s[(kk + 3) * NC + c], acc[c]);
        }
    }
    float* outp = h2 + (size_t)r * NC;       // 160 B rows, 16 B aligned
#pragma unroll
    for (int c = 0; c < NC; c += 4)
        *(float4*)&outp[c] = make_float4(acc[c], acc[c + 1], acc[c + 2], acc[c + 3]);
}

// ---------- edge scatter, 40-wide ----------
__global__ __launch_bounds__(256) void scatter40_k(const int* __restrict__ src,
                                                   const int* __restrict__ dst,
                                                   const float* __restrict__ w,
                                                   const float* __restrict__ dinv,
                                                   const float* __restrict__ h,
                                                   float* __restrict__ agg) {
    const int e = blockIdx.x * 4 + (threadIdx.x >> 6);
    if (e >= ETOT) return;
    const int lane = threadIdx.x & 63;
    int s, d; float ww;
    if (e < NE) { s = src[e]; d = dst[e]; ww = w[e]; }
    else        { s = d = e - NE; ww = 1.0f; }
    const float nrm = dinv[s] * ww * dinv[d];
    if (lane < NC)
        atomicAdd(&agg[(size_t)d * NC + lane], h[(size_t)s * NC + lane] * nrm);
}

// ---------- b2 + in-place log_softmax over 40 classes ----------
__global__ __launch_bounds__(256) void logsm_k(float* __restrict__ out,
                                               const float* __restrict__ b2) {
    const int r = blockIdx.x * 4 + (threadIdx.x >> 6);
    if (r >= NN) return;
    const int lane = threadIdx.x & 63;
    float v = -INFINITY;
    if (lane < NC) v = out[(size_t)r * NC + lane] + b2[lane];
    float m = v;
#pragma unroll
    for (int off = 32; off >= 1; off >>= 1)
        m = fmaxf(m, __shfl_xor(m, off, 64));
    float ex = (lane < NC) ? expf(v - m) : 0.f;
    float s = ex;
#pragma unroll
    for (int off = 32; off >= 1; off >>= 1)
        s += __shfl_xor(s, off, 64);
    if (lane < NC) out[(size_t)r * NC + lane] = v - m - logf(s);
}

extern "C" void kernel_launch(void* const* d_in, const int* in_sizes, int n_in,
                              void* d_out, int out_size, void* d_ws, size_t ws_size,
                              hipStream_t stream) {
    const float* x  = (const float*)d_in[0];
    const int*   ei = (const int*)d_in[1];     // [2, E] flat: row0=src, row1=dst
    const float* ea = (const float*)d_in[2];
    const float* W1 = (const float*)d_in[3];
    const float* b1 = (const float*)d_in[4];
    const float* W2 = (const float*)d_in[5];
    const float* b2 = (const float*)d_in[6];
    const int* src = ei;
    const int* dst = ei + NE;
    float* out = (float*)d_out;

    char* ws = (char*)d_ws;
    float* dinv = (float*)(ws + 0);            //   400,000 B (N f32)
    float* h1   = (float*)(ws + 400000);       // 25,600,000 B (N x 64)
    float* agg1 = (float*)(ws + 26000000);     // 25,600,000 B (N x 64)
    float* h2   = (float*)(ws + 51600000);     // 16,000,000 B (N x 40)
                                               // total 67.6 MB

    // zero the atomic accumulation targets (d_ws/d_out are poisoned 0xAA)
    hipMemsetAsync(agg1, 0, (size_t)NN * HID * sizeof(float), stream);
    hipMemsetAsync(out,  0, (size_t)NN * NC  * sizeof(float), stream);

    init_deg_k <<<(NN + 255) / 256, 256, 0, stream>>>(dinv);
    accum_deg_k<<<(NE + 255) / 256, 256, 0, stream>>>(dst, ea, dinv);
    dinv_k     <<<(NN + 255) / 256, 256, 0, stream>>>(dinv);

    gemm1_k    <<<NN / 32, 256, 0, stream>>>(x, W1, h1);
    scatter64_k<<<(ETOT + 3) / 4, 256, 0, stream>>>(src, dst, ea, dinv, h1, agg1);
    gemm2_k    <<<(NN + 255) / 256, 256, 0, stream>>>(agg1, b1, W2, h2);
    scatter40_k<<<(ETOT + 3) / 4, 256, 0, stream>>>(src, dst, ea, dinv, h2, out);
    logsm_k    <<<(NN + 3) / 4, 256, 0, stream>>>(out, b2);
}

// Round 2
// 666.612 us; speedup vs baseline: 1.4999x; 1.4999x over previous
//
#include <hip/hip_runtime.h>
#include <math.h>

#define NN   100000
#define NE   1600000
#define FIN  256
#define HID  64
#define NC   40
#define NB   ((NN + 255) / 256)   // 391 scan blocks

// ---------- init: deg=1 (self-loop), cnt=0 ----------
__global__ __launch_bounds__(256) void init_k(float* __restrict__ deg, int* __restrict__ cnt) {
    int i = blockIdx.x * 256 + threadIdx.x;
    if (i < NN) { deg[i] = 1.0f; cnt[i] = 0; }
}

// ---------- per-edge: weighted degree + in-degree count ----------
__global__ __launch_bounds__(256) void edge_count_k(const int* __restrict__ dst,
                                                    const float* __restrict__ w,
                                                    float* __restrict__ deg,
                                                    int* __restrict__ cnt) {
    int e = blockIdx.x * 256 + threadIdx.x;
    if (e < NE) {
        int d = dst[e];
        atomicAdd(&deg[d], w[e]);
        atomicAdd(&cnt[d], 1);
    }
}

__global__ __launch_bounds__(256) void dinv_k(float* __restrict__ deg) {
    int i = blockIdx.x * 256 + threadIdx.x;
    if (i < NN) {
        float d = deg[i];
        deg[i] = (d > 0.f) ? rsqrtf(fmaxf(d, 1e-30f)) : 0.f;
    }
}

// ---------- scan stage 1: per-block sums of cnt ----------
__global__ __launch_bounds__(256) void scan1_k(const int* __restrict__ cnt, int* __restrict__ bsum) {
    int i = blockIdx.x * 256 + threadIdx.x;
    int v = (i < NN) ? cnt[i] : 0;
#pragma unroll
    for (int off = 32; off >= 1; off >>= 1) v += __shfl_xor(v, off, 64);
    __shared__ int ws[4];
    if ((threadIdx.x & 63) == 0) ws[threadIdx.x >> 6] = v;
    __syncthreads();
    if (threadIdx.x == 0) bsum[blockIdx.x] = ws[0] + ws[1] + ws[2] + ws[3];
}

// ---------- scan stage 2: exclusive scan of 391 block sums (single block) ----------
__global__ __launch_bounds__(512) void scan2_k(const int* __restrict__ bsum, int* __restrict__ boff,
                                               int* __restrict__ row_start) {
    __shared__ int tmp[512];
    int t = threadIdx.x;
    int v = (t < NB) ? bsum[t] : 0;
    tmp[t] = v;
    __syncthreads();
    for (int off = 1; off < 512; off <<= 1) {
        int add = (t >= off) ? tmp[t - off] : 0;
        __syncthreads();
        tmp[t] += add;
        __syncthreads();
    }
    if (t < NB) boff[t] = tmp[t] - v;      // exclusive
    if (t == 0) row_start[NN] = NE;
}

// ---------- scan stage 3: within-block exclusive scan + offset -> row_start, cursor ----------
__global__ __launch_bounds__(256) void scan3_k(const int* __restrict__ cnt, const int* __restrict__ boff,
                                               int* __restrict__ row_start, int* __restrict__ cursor) {
    __shared__ int tmp[256];
    int t = threadIdx.x;
    int i = blockIdx.x * 256 + t;
    int v = (i < NN) ? cnt[i] : 0;
    tmp[t] = v;
    __syncthreads();
    for (int off = 1; off < 256; off <<= 1) {
        int add = (t >= off) ? tmp[t - off] : 0;
        __syncthreads();
        tmp[t] += add;
        __syncthreads();
    }
    if (i < NN) {
        int rs = boff[blockIdx.x] + tmp[t] - v;   // exclusive scan value
        row_start[i] = rs;
        cursor[i] = rs;
    }
}

// ---------- CSR fill: (src, norm) per edge, bucketed by dst ----------
__global__ __launch_bounds__(256) void fill_k(const int* __restrict__ src, const int* __restrict__ dst,
                                              const float* __restrict__ w, const float* __restrict__ dinv,
                                              int* __restrict__ cursor, int2* __restrict__ e8) {
    int e = blockIdx.x * 256 + threadIdx.x;
    if (e < NE) {
        int s = src[e], d = dst[e];
        float nrm = dinv[s] * w[e] * dinv[d];
        int p = atomicAdd(&cursor[d], 1);
        e8[p] = make_int2(s, __float_as_int(nrm));
    }
}

// ---------- layer-1 GEMM: h1 = x @ W1 ----------
__global__ __launch_bounds__(256) void gemm1_k(const float* __restrict__ x,
                                               const float* __restrict__ W1,
                                               float* __restrict__ h1) {
    __shared__ float xs[32 * FIN];           // 32 KB
    const int base_row = blockIdx.x * 32;    // NN % 32 == 0
    const float4* __restrict__ x4 = (const float4*)(x + (size_t)base_row * FIN);
    float4* xs4 = (float4*)xs;
#pragma unroll
    for (int i = 0; i < 8; ++i)
        xs4[threadIdx.x + i * 256] = x4[threadIdx.x + i * 256];
    __syncthreads();

    const int wave = threadIdx.x >> 6;
    const int lane = threadIdx.x & 63;       // output column
    const int r0 = wave * 8;                 // 8 rows per wave
    float acc[8];
#pragma unroll
    for (int j = 0; j < 8; ++j) acc[j] = 0.f;

    for (int kk = 0; kk < FIN; kk += 4) {
        float w0 = W1[(kk + 0) * HID + lane];
        float w1 = W1[(kk + 1) * HID + lane];
        float w2 = W1[(kk + 2) * HID + lane];
        float w3 = W1[(kk + 3) * HID + lane];
#pragma unroll
        for (int j = 0; j < 8; ++j) {
            float4 xq = *(const float4*)&xs[(r0 + j) * FIN + kk];  // wave-broadcast
            acc[j] = fmaf(xq.x, w0, acc[j]);
            acc[j] = fmaf(xq.y, w1, acc[j]);
            acc[j] = fmaf(xq.z, w2, acc[j]);
            acc[j] = fmaf(xq.w, w3, acc[j]);
        }
    }
#pragma unroll
    for (int j = 0; j < 8; ++j)
        h1[(size_t)(base_row + r0 + j) * HID + lane] = acc[j];
}

// ---------- gather aggregation, 64 channels: one wave per node ----------
__global__ __launch_bounds__(256) void gather64_k(const int* __restrict__ row_start,
                                                  const int2* __restrict__ e8,
                                                  const float* __restrict__ dinv,
                                                  const float* __restrict__ h,
                                                  float* __restrict__ agg) {
    const int v = blockIdx.x * 4 + (threadIdx.x >> 6);   // grid sized so v < NN
    const int lane = threadIdx.x & 63;
    const int i0 = row_start[v], i1 = row_start[v + 1];
    float acc0 = 0.f, acc1 = 0.f;
    int i = i0;
    for (; i + 2 <= i1; i += 2) {
        int2 a = e8[i];
        int2 b = e8[i + 1];
        acc0 = fmaf(h[(size_t)a.x * HID + lane], __int_as_float(a.y), acc0);
        acc1 = fmaf(h[(size_t)b.x * HID + lane], __int_as_float(b.y), acc1);
    }
    if (i < i1) {
        int2 a = e8[i];
        acc0 = fmaf(h[(size_t)a.x * HID + lane], __int_as_float(a.y), acc0);
    }
    float di = dinv[v];                                  // self-loop: norm = dinv^2
    acc0 = fmaf(h[(size_t)v * HID + lane], di * di, acc0 + acc1);
    agg[(size_t)v * HID + lane] = acc0;
}

// ---------- layer-2 GEMM (fused relu(agg1+b1)): h2 = relu(agg1+b1) @ W2 ----------
__global__ __launch_bounds__(256) void gemm2_k(const float* __restrict__ agg1,
                                               const float* __restrict__ b1,
                                               const float* __restrict__ W2,
                                               float* __restrict__ h2) {
    __shared__ float w2s[HID * NC];
    __shared__ float b1s[HID];
    for (int i = threadIdx.x; i < HID * NC; i += 256) w2s[i] = W2[i];
    if (threadIdx.x < HID) b1s[threadIdx.x] = b1[threadIdx.x];
    __syncthreads();

    const int r = blockIdx.x * 256 + threadIdx.x;
    if (r >= NN) return;
    float acc[NC];
#pragma unroll
    for (int c = 0; c < NC; ++c) acc[c] = 0.f;

    const float4* row4 = (const float4*)(agg1 + (size_t)r * HID);
    for (int kk = 0; kk < HID; kk += 4) {
        float4 v = row4[kk >> 2];
        float xr0 = fmaxf(v.x + b1s[kk + 0], 0.f);
        float xr1 = fmaxf(v.y + b1s[kk + 1], 0.f);
        float xr2 = fmaxf(v.z + b1s[kk + 2], 0.f);
        float xr3 = fmaxf(v.w + b1s[kk + 3], 0.f);
#pragma unroll
        for (int c = 0; c < NC; ++c) {
            acc[c] = fmaf(xr0, w2s[(kk + 0) * NC + c], acc[c]);
            acc[c] = fmaf(xr1, w2s[(kk + 1) * NC + c], acc[c]);
            acc[c] = fmaf(xr2, w2s[(kk + 2) * NC + c], acc[c]);
            acc[c] = fmaf(xr3, w2s[(kk + 3) * NC + c], acc[c]);
        }
    }
    float* outp = h2 + (size_t)r * NC;
#pragma unroll
    for (int c = 0; c < NC; c += 4)
        *(float4*)&outp[c] = make_float4(acc[c], acc[c + 1], acc[c + 2], acc[c + 3]);
}

// ---------- gather 40 channels + b2 + log_softmax, fused: one wave per node ----------
__global__ __launch_bounds__(256) void gather40_logsm_k(const int* __restrict__ row_start,
                                                        const int2* __restrict__ e8,
                                                        const float* __restrict__ dinv,
                                                        const float* __restrict__ h,
                                                        const float* __restrict__ b2,
                                                        float* __restrict__ out) {
    const int v = blockIdx.x * 4 + (threadIdx.x >> 6);
    const int lane = threadIdx.x & 63;
    const int i0 = row_start[v], i1 = row_start[v + 1];
    const int cl = (lane < NC) ? lane : 0;               // keep loads in-bounds for idle lanes
    float acc0 = 0.f, acc1 = 0.f;
    int i = i0;
    for (; i + 2 <= i1; i += 2) {
        int2 a = e8[i];
        int2 b = e8[i + 1];
        acc0 = fmaf(h[(size_t)a.x * NC + cl], __int_as_float(a.y), acc0);
        acc1 = fmaf(h[(size_t)b.x * NC + cl], __int_as_float(b.y), acc1);
    }
    if (i < i1) {
        int2 a = e8[i];
        acc0 = fmaf(h[(size_t)a.x * NC + cl], __int_as_float(a.y), acc0);
    }
    float di = dinv[v];
    acc0 = fmaf(h[(size_t)v * NC + cl], di * di, acc0 + acc1);
    float vv = acc0 + b2[cl];

    float m = (lane < NC) ? vv : -INFINITY;
#pragma unroll
    for (int off = 32; off >= 1; off >>= 1) m = fmaxf(m, __shfl_xor(m, off, 64));
    float ex = (lane < NC) ? __expf(vv - m) : 0.f;
    float s = ex;
#pragma unroll
    for (int off = 32; off >= 1; off >>= 1) s += __shfl_xor(s, off, 64);
    if (lane < NC) out[(size_t)v * NC + lane] = vv - m - __logf(s);
}

extern "C" void kernel_launch(void* const* d_in, const int* in_sizes, int n_in,
                              void* d_out, int out_size, void* d_ws, size_t ws_size,
                              hipStream_t stream) {
    const float* x  = (const float*)d_in[0];
    const int*   ei = (const int*)d_in[1];     // [2, E]: row0=src, row1=dst
    const float* ea = (const float*)d_in[2];
    const float* W1 = (const float*)d_in[3];
    const float* b1 = (const float*)d_in[4];
    const float* W2 = (const float*)d_in[5];
    const float* b2 = (const float*)d_in[6];
    const int* src = ei;
    const int* dst = ei + NE;
    float* out = (float*)d_out;

    char* ws = (char*)d_ws;
    float* dinv      = (float*)(ws + 0);           //   400,000 B
    int*   cnt       = (int*)  (ws + 400000);      //   400,000 B
    int*   row_start = (int*)  (ws + 800000);      //   400,016 B (NN+1)
    int*   cursor    = (int*)  (ws + 1200128);     //   400,000 B
    int*   bsum      = (int*)  (ws + 1600128);     //     2,048 B
    int*   boff      = (int*)  (ws + 1602176);     //     2,048 B
    int2*  e8        = (int2*) (ws + 1604224);     // 12,800,000 B
    float* h1        = (float*)(ws + 14404224);    // 25,600,000 B
    float* agg1      = (float*)(ws + 40004224);    // 25,600,000 B
    float* h2        = h1;                         // h1 dead after gather64; 16 MB <= 25.6 MB
                                                   // total 65.6 MB

    const int NBE = (NE + 255) / 256;

    init_k      <<<NB, 256, 0, stream>>>(dinv, cnt);
    edge_count_k<<<NBE, 256, 0, stream>>>(dst, ea, dinv, cnt);
    dinv_k      <<<NB, 256, 0, stream>>>(dinv);

    scan1_k<<<NB, 256, 0, stream>>>(cnt, bsum);
    scan2_k<<<1, 512, 0, stream>>>(bsum, boff, row_start);
    scan3_k<<<NB, 256, 0, stream>>>(cnt, boff, row_start, cursor);
    fill_k <<<NBE, 256, 0, stream>>>(src, dst, ea, dinv, cursor, e8);

    gemm1_k         <<<NN / 32, 256, 0, stream>>>(x, W1, h1);
    gather64_k      <<<NN / 4, 256, 0, stream>>>(row_start, e8, dinv, h1, agg1);
    gemm2_k         <<<(NN + 255) / 256, 256, 0, stream>>>(agg1, b1, W2, h2);
    gather40_logsm_k<<<NN / 4, 256, 0, stream>>>(row_start, e8, dinv, h2, b2, out);
}

// Round 3
// 555.650 us; speedup vs baseline: 1.7995x; 1.1997x over previous
//
#include <hip/hip_runtime.h>
#include <math.h>

#define NN   100000
#define NE   1600000
#define FIN  256
#define HID  64
#define NC   40
#define NB   ((NN + 255) / 256)   // 391
#define NBE  ((NE + 255) / 256)   // 6250
#define NG1  (NN / 32)            // 3125 gemm1 blocks

// ---------- fused: gemm1 (h1 = x@W1) + in-degree count ----------
// bx % 3 == 0 -> gemm1 block (3125 of them), else count block (6250).
__global__ __launch_bounds__(256) void fused_gemm1_count_k(const float* __restrict__ x,
                                                           const float* __restrict__ W1,
                                                           float* __restrict__ h1,
                                                           const int* __restrict__ dst,
                                                           int* __restrict__ cnt) {
    __shared__ float xs[32 * FIN];           // 32 KB -> 5 blocks/CU
    const int bx = blockIdx.x;
    if (bx % 3 != 0) {                       // ---- count path ----
        const int c = bx - 1 - bx / 3;       // 0..6249
        const int e = c * 256 + threadIdx.x;
        if (e < NE) atomicAdd(&cnt[dst[e]], 1);
        return;
    }
    // ---- gemm1 path ----
    const int g = bx / 3;                    // 0..3124
    const int base_row = g * 32;
    const float4* __restrict__ x4 = (const float4*)(x + (size_t)base_row * FIN);
    float4* xs4 = (float4*)xs;
#pragma unroll
    for (int i = 0; i < 8; ++i)
        xs4[threadIdx.x + i * 256] = x4[threadIdx.x + i * 256];
    __syncthreads();

    const int wave = threadIdx.x >> 6;
    const int lane = threadIdx.x & 63;
    const int r0 = wave * 8;
    float acc[8];
#pragma unroll
    for (int j = 0; j < 8; ++j) acc[j] = 0.f;

    for (int kk = 0; kk < FIN; kk += 4) {
        float w0 = W1[(kk + 0) * HID + lane];
        float w1 = W1[(kk + 1) * HID + lane];
        float w2 = W1[(kk + 2) * HID + lane];
        float w3 = W1[(kk + 3) * HID + lane];
#pragma unroll
        for (int j = 0; j < 8; ++j) {
            float4 xq = *(const float4*)&xs[(r0 + j) * FIN + kk];
            acc[j] = fmaf(xq.x, w0, acc[j]);
            acc[j] = fmaf(xq.y, w1, acc[j]);
            acc[j] = fmaf(xq.z, w2, acc[j]);
            acc[j] = fmaf(xq.w, w3, acc[j]);
        }
    }
#pragma unroll
    for (int j = 0; j < 8; ++j)
        h1[(size_t)(base_row + r0 + j) * HID + lane] = acc[j];
}

// ---------- scan stage 1 ----------
__global__ __launch_bounds__(256) void scan1_k(const int* __restrict__ cnt, int* __restrict__ bsum) {
    int i = blockIdx.x * 256 + threadIdx.x;
    int v = (i < NN) ? cnt[i] : 0;
#pragma unroll
    for (int off = 32; off >= 1; off >>= 1) v += __shfl_xor(v, off, 64);
    __shared__ int ws[4];
    if ((threadIdx.x & 63) == 0) ws[threadIdx.x >> 6] = v;
    __syncthreads();
    if (threadIdx.x == 0) bsum[blockIdx.x] = ws[0] + ws[1] + ws[2] + ws[3];
}

// ---------- scan stage 2 ----------
__global__ __launch_bounds__(512) void scan2_k(const int* __restrict__ bsum, int* __restrict__ boff,
                                               int* __restrict__ row_start) {
    __shared__ int tmp[512];
    int t = threadIdx.x;
    int v = (t < NB) ? bsum[t] : 0;
    tmp[t] = v;
    __syncthreads();
    for (int off = 1; off < 512; off <<= 1) {
        int add = (t >= off) ? tmp[t - off] : 0;
        __syncthreads();
        tmp[t] += add;
        __syncthreads();
    }
    if (t < NB) boff[t] = tmp[t] - v;
    if (t == 0) row_start[NN] = NE;
}

// ---------- scan stage 3 ----------
__global__ __launch_bounds__(256) void scan3_k(const int* __restrict__ cnt, const int* __restrict__ boff,
                                               int* __restrict__ row_start, int* __restrict__ cursor) {
    __shared__ int tmp[256];
    int t = threadIdx.x;
    int i = blockIdx.x * 256 + t;
    int v = (i < NN) ? cnt[i] : 0;
    tmp[t] = v;
    __syncthreads();
    for (int off = 1; off < 256; off <<= 1) {
        int add = (t >= off) ? tmp[t - off] : 0;
        __syncthreads();
        tmp[t] += add;
        __syncthreads();
    }
    if (i < NN) {
        int rs = boff[blockIdx.x] + tmp[t] - v;
        row_start[i] = rs;
        cursor[i] = rs;
    }
}

// ---------- CSR fill: (src, w) bucketed by dst ----------
__global__ __launch_bounds__(256) void fill_k(const int* __restrict__ src, const int* __restrict__ dst,
                                              const float* __restrict__ w,
                                              int* __restrict__ cursor, int2* __restrict__ e8) {
    int e = blockIdx.x * 256 + threadIdx.x;
    if (e < NE) {
        int d = dst[e];
        int p = atomicAdd(&cursor[d], 1);
        e8[p] = make_int2(src[e], __float_as_int(w[e]));
    }
}

// ---------- per-node: deg = 1 + sum(w) over CSR row -> dinv (wave per node) ----------
__global__ __launch_bounds__(256) void degrow_k(const int* __restrict__ row_start,
                                                const int2* __restrict__ e8,
                                                float* __restrict__ dinv) {
    const int v = blockIdx.x * 4 + (threadIdx.x >> 6);
    const int lane = threadIdx.x & 63;
    const int i0 = row_start[v], i1 = row_start[v + 1];
    float s = 0.f;
    for (int i = i0 + lane; i < i1; i += 64) s += __int_as_float(e8[i].y);
#pragma unroll
    for (int off = 32; off >= 1; off >>= 1) s += __shfl_xor(s, off, 64);
    if (lane == 0) dinv[v] = rsqrtf(1.0f + s);   // deg >= 1 always (self-loop)
}

// ---------- gather 64ch, norm on the fly, unroll-4 ----------
__global__ __launch_bounds__(256) void gather64_k(const int* __restrict__ row_start,
                                                  const int2* __restrict__ e8,
                                                  const float* __restrict__ dinv,
                                                  const float* __restrict__ h,
                                                  float* __restrict__ agg) {
    const int v = blockIdx.x * 4 + (threadIdx.x >> 6);
    const int lane = threadIdx.x & 63;
    const int i0 = row_start[v], i1 = row_start[v + 1];
    float acc0 = 0.f, acc1 = 0.f, acc2 = 0.f, acc3 = 0.f;
    int i = i0;
    for (; i + 4 <= i1; i += 4) {
        int2 a = e8[i + 0], b = e8[i + 1], c = e8[i + 2], d = e8[i + 3];
        float wa = dinv[a.x] * __int_as_float(a.y);
        float wb = dinv[b.x] * __int_as_float(b.y);
        float wc = dinv[c.x] * __int_as_float(c.y);
        float wd = dinv[d.x] * __int_as_float(d.y);
        acc0 = fmaf(h[(size_t)a.x * HID + lane], wa, acc0);
        acc1 = fmaf(h[(size_t)b.x * HID + lane], wb, acc1);
        acc2 = fmaf(h[(size_t)c.x * HID + lane], wc, acc2);
        acc3 = fmaf(h[(size_t)d.x * HID + lane], wd, acc3);
    }
    for (; i < i1; ++i) {
        int2 a = e8[i];
        acc0 = fmaf(h[(size_t)a.x * HID + lane], dinv[a.x] * __int_as_float(a.y), acc0);
    }
    const float dv = dinv[v];
    float r = dv * ((acc0 + acc1) + (acc2 + acc3));
    r = fmaf(dv * dv, h[(size_t)v * HID + lane], r);
    agg[(size_t)v * HID + lane] = r;
}

// ---------- layer-2 GEMM (fused relu(agg1+b1)) ----------
__global__ __launch_bounds__(256) void gemm2_k(const float* __restrict__ agg1,
                                               const float* __restrict__ b1,
                                               const float* __restrict__ W2,
                                               float* __restrict__ h2) {
    __shared__ float w2s[HID * NC];
    __shared__ float b1s[HID];
    for (int i = threadIdx.x; i < HID * NC; i += 256) w2s[i] = W2[i];
    if (threadIdx.x < HID) b1s[threadIdx.x] = b1[threadIdx.x];
    __syncthreads();

    const int r = blockIdx.x * 256 + threadIdx.x;
    if (r >= NN) return;
    float acc[NC];
#pragma unroll
    for (int c = 0; c < NC; ++c) acc[c] = 0.f;

    const float4* row4 = (const float4*)(agg1 + (size_t)r * HID);
    for (int kk = 0; kk < HID; kk += 4) {
        float4 v = row4[kk >> 2];
        float xr0 = fmaxf(v.x + b1s[kk + 0], 0.f);
        float xr1 = fmaxf(v.y + b1s[kk + 1], 0.f);
        float xr2 = fmaxf(v.z + b1s[kk + 2], 0.f);
        float xr3 = fmaxf(v.w + b1s[kk + 3], 0.f);
#pragma unroll
        for (int c = 0; c < NC; ++c) {
            acc[c] = fmaf(xr0, w2s[(kk + 0) * NC + c], acc[c]);
            acc[c] = fmaf(xr1, w2s[(kk + 1) * NC + c], acc[c]);
            acc[c] = fmaf(xr2, w2s[(kk + 2) * NC + c], acc[c]);
            acc[c] = fmaf(xr3, w2s[(kk + 3) * NC + c], acc[c]);
        }
    }
    float* outp = h2 + (size_t)r * NC;
#pragma unroll
    for (int c = 0; c < NC; c += 4)
        *(float4*)&outp[c] = make_float4(acc[c], acc[c + 1], acc[c + 2], acc[c + 3]);
}

// ---------- gather 40ch + b2 + log_softmax, norm on the fly, unroll-4 ----------
__global__ __launch_bounds__(256) void gather40_logsm_k(const int* __restrict__ row_start,
                                                        const int2* __restrict__ e8,
                                                        const float* __restrict__ dinv,
                                                        const float* __restrict__ h,
                                                        const float* __restrict__ b2,
                                                        float* __restrict__ out) {
    const int v = blockIdx.x * 4 + (threadIdx.x >> 6);
    const int lane = threadIdx.x & 63;
    const int i0 = row_start[v], i1 = row_start[v + 1];
    const int cl = (lane < NC) ? lane : 0;
    float acc0 = 0.f, acc1 = 0.f, acc2 = 0.f, acc3 = 0.f;
    int i = i0;
    for (; i + 4 <= i1; i += 4) {
        int2 a = e8[i + 0], b = e8[i + 1], c = e8[i + 2], d = e8[i + 3];
        float wa = dinv[a.x] * __int_as_float(a.y);
        float wb = dinv[b.x] * __int_as_float(b.y);
        float wc = dinv[c.x] * __int_as_float(c.y);
        float wd = dinv[d.x] * __int_as_float(d.y);
        acc0 = fmaf(h[(size_t)a.x * NC + cl], wa, acc0);
        acc1 = fmaf(h[(size_t)b.x * NC + cl], wb, acc1);
        acc2 = fmaf(h[(size_t)c.x * NC + cl], wc, acc2);
        acc3 = fmaf(h[(size_t)d.x * NC + cl], wd, acc3);
    }
    for (; i < i1; ++i) {
        int2 a = e8[i];
        acc0 = fmaf(h[(size_t)a.x * NC + cl], dinv[a.x] * __int_as_float(a.y), acc0);
    }
    const float dv = dinv[v];
    float vv = dv * ((acc0 + acc1) + (acc2 + acc3));
    vv = fmaf(dv * dv, h[(size_t)v * NC + cl], vv);
    vv += b2[cl];

    float m = (lane < NC) ? vv : -INFINITY;
#pragma unroll
    for (int off = 32; off >= 1; off >>= 1) m = fmaxf(m, __shfl_xor(m, off, 64));
    float ex = (lane < NC) ? __expf(vv - m) : 0.f;
    float s = ex;
#pragma unroll
    for (int off = 32; off >= 1; off >>= 1) s += __shfl_xor(s, off, 64);
    if (lane < NC) out[(size_t)v * NC + lane] = vv - m - __logf(s);
}

extern "C" void kernel_launch(void* const* d_in, const int* in_sizes, int n_in,
                              void* d_out, int out_size, void* d_ws, size_t ws_size,
                              hipStream_t stream) {
    const float* x  = (const float*)d_in[0];
    const int*   ei = (const int*)d_in[1];     // [2, E]: row0=src, row1=dst
    const float* ea = (const float*)d_in[2];
    const float* W1 = (const float*)d_in[3];
    const float* b1 = (const float*)d_in[4];
    const float* W2 = (const float*)d_in[5];
    const float* b2 = (const float*)d_in[6];
    const int* src = ei;
    const int* dst = ei + NE;
    float* out = (float*)d_out;

    char* ws = (char*)d_ws;
    float* dinv      = (float*)(ws + 0);           //   400,000 B
    int*   cnt       = (int*)  (ws + 400000);      //   400,000 B
    int*   row_start = (int*)  (ws + 800000);      //   400,016 B (NN+1)
    int*   cursor    = (int*)  (ws + 1200128);     //   400,000 B
    int*   bsum      = (int*)  (ws + 1600128);     //     2,048 B
    int*   boff      = (int*)  (ws + 1602176);     //     2,048 B
    int2*  e8        = (int2*) (ws + 1604224);     // 12,800,000 B
    float* h1        = (float*)(ws + 14404224);    // 25,600,000 B
    float* agg1      = (float*)(ws + 40004224);    // 25,600,000 B
    float* h2        = h1;                         // h1 dead after gather64

    hipMemsetAsync(cnt, 0, (size_t)NN * sizeof(int), stream);

    fused_gemm1_count_k<<<NG1 * 3, 256, 0, stream>>>(x, W1, h1, dst, cnt);

    scan1_k<<<NB, 256, 0, stream>>>(cnt, bsum);
    scan2_k<<<1, 512, 0, stream>>>(bsum, boff, row_start);
    scan3_k<<<NB, 256, 0, stream>>>(cnt, boff, row_start, cursor);
    fill_k <<<NBE, 256, 0, stream>>>(src, dst, ea, cursor, e8);
    degrow_k<<<NN / 4, 256, 0, stream>>>(row_start, e8, dinv);

    gather64_k      <<<NN / 4, 256, 0, stream>>>(row_start, e8, dinv, h1, agg1);
    gemm2_k         <<<(NN + 255) / 256, 256, 0, stream>>>(agg1, b1, W2, h2);
    gather40_logsm_k<<<NN / 4, 256, 0, stream>>>(row_start, e8, dinv, h2, b2, out);
}

// Round 4
// 483.384 us; speedup vs baseline: 2.0685x; 1.1495x over previous
//
#include <hip/hip_runtime.h>
#include <math.h>

#define NN   100000
#define NE   1600000
#define FIN  256
#define HID  64
#define NC   40
#define NB   ((NN + 255) / 256)   // 391
#define NBE  ((NE + 255) / 256)   // 6250
#define NG1  (NN / 32)            // 3125 gemm1 blocks

// ---------- fused: gemm1 (h1 = x@W1) + in-degree count + rank ----------
// bx % 3 == 0 -> gemm1 block (3125), else count block (6250).
__global__ __launch_bounds__(256) void fused_gemm1_count_k(const float* __restrict__ x,
                                                           const float* __restrict__ W1,
                                                           float* __restrict__ h1,
                                                           const int* __restrict__ dst,
                                                           int* __restrict__ cnt,
                                                           int* __restrict__ rank) {
    __shared__ float xs[32 * FIN];           // 32 KB
    const int bx = blockIdx.x;
    if (bx % 3 != 0) {                       // ---- count path ----
        const int c = bx - 1 - bx / 3;       // 0..6249
        const int e = c * 256 + threadIdx.x;
        if (e < NE) {
            int p = atomicAdd(&cnt[dst[e]], 1);
            rank[e] = p;                     // coalesced store of in-bucket rank
        }
        return;
    }
    // ---- gemm1 path ----
    const int g = bx / 3;                    // 0..3124
    const int base_row = g * 32;
    const float4* __restrict__ x4 = (const float4*)(x + (size_t)base_row * FIN);
    float4* xs4 = (float4*)xs;
#pragma unroll
    for (int i = 0; i < 8; ++i)
        xs4[threadIdx.x + i * 256] = x4[threadIdx.x + i * 256];
    __syncthreads();

    const int wave = threadIdx.x >> 6;
    const int lane = threadIdx.x & 63;
    const int r0 = wave * 8;
    float acc[8];
#pragma unroll
    for (int j = 0; j < 8; ++j) acc[j] = 0.f;

    for (int kk = 0; kk < FIN; kk += 4) {
        float w0 = W1[(kk + 0) * HID + lane];
        float w1 = W1[(kk + 1) * HID + lane];
        float w2 = W1[(kk + 2) * HID + lane];
        float w3 = W1[(kk + 3) * HID + lane];
#pragma unroll
        for (int j = 0; j < 8; ++j) {
            float4 xq = *(const float4*)&xs[(r0 + j) * FIN + kk];
            acc[j] = fmaf(xq.x, w0, acc[j]);
            acc[j] = fmaf(xq.y, w1, acc[j]);
            acc[j] = fmaf(xq.z, w2, acc[j]);
            acc[j] = fmaf(xq.w, w3, acc[j]);
        }
    }
#pragma unroll
    for (int j = 0; j < 8; ++j)
        h1[(size_t)(base_row + r0 + j) * HID + lane] = acc[j];
}

// ---------- scan stage 1 ----------
__global__ __launch_bounds__(256) void scan1_k(const int* __restrict__ cnt, int* __restrict__ bsum) {
    int i = blockIdx.x * 256 + threadIdx.x;
    int v = (i < NN) ? cnt[i] : 0;
#pragma unroll
    for (int off = 32; off >= 1; off >>= 1) v += __shfl_xor(v, off, 64);
    __shared__ int ws[4];
    if ((threadIdx.x & 63) == 0) ws[threadIdx.x >> 6] = v;
    __syncthreads();
    if (threadIdx.x == 0) bsum[blockIdx.x] = ws[0] + ws[1] + ws[2] + ws[3];
}

// ---------- scan stage 2 ----------
__global__ __launch_bounds__(512) void scan2_k(const int* __restrict__ bsum, int* __restrict__ boff,
                                               int* __restrict__ row_start) {
    __shared__ int tmp[512];
    int t = threadIdx.x;
    int v = (t < NB) ? bsum[t] : 0;
    tmp[t] = v;
    __syncthreads();
    for (int off = 1; off < 512; off <<= 1) {
        int add = (t >= off) ? tmp[t - off] : 0;
        __syncthreads();
        tmp[t] += add;
        __syncthreads();
    }
    if (t < NB) boff[t] = tmp[t] - v;
    if (t == 0) row_start[NN] = NE;
}

// ---------- scan stage 3 ----------
__global__ __launch_bounds__(256) void scan3_k(const int* __restrict__ cnt, const int* __restrict__ boff,
                                               int* __restrict__ row_start) {
    __shared__ int tmp[256];
    int t = threadIdx.x;
    int i = blockIdx.x * 256 + t;
    int v = (i < NN) ? cnt[i] : 0;
    tmp[t] = v;
    __syncthreads();
    for (int off = 1; off < 256; off <<= 1) {
        int add = (t >= off) ? tmp[t - off] : 0;
        __syncthreads();
        tmp[t] += add;
        __syncthreads();
    }
    if (i < NN) row_start[i] = boff[blockIdx.x] + tmp[t] - v;
}

// ---------- CSR fill, atomic-free: pos = row_start[dst] + rank ----------
__global__ __launch_bounds__(256) void fill_k(const int* __restrict__ src, const int* __restrict__ dst,
                                              const float* __restrict__ w, const int* __restrict__ rank,
                                              const int* __restrict__ row_start,
                                              int2* __restrict__ e8) {
    int e = blockIdx.x * 256 + threadIdx.x;
    if (e < NE) {
        int d = dst[e];
        int pos = row_start[d] + rank[e];
        e8[pos] = make_int2(src[e], __float_as_int(w[e]));
    }
}

// ---------- per-node: deg = 1 + sum(w) over CSR row -> dinv (wave per node) ----------
__global__ __launch_bounds__(256) void degrow_k(const int* __restrict__ row_start,
                                                const int2* __restrict__ e8,
                                                float* __restrict__ dinv) {
    const int v = blockIdx.x * 4 + (threadIdx.x >> 6);
    const int lane = threadIdx.x & 63;
    const int i0 = row_start[v], i1 = row_start[v + 1];
    float s = 0.f;
    for (int i = i0 + lane; i < i1; i += 64) s += __int_as_float(e8[i].y);
#pragma unroll
    for (int off = 32; off >= 1; off >>= 1) s += __shfl_xor(s, off, 64);
    if (lane == 0) dinv[v] = rsqrtf(1.0f + s);
}

// ---------- gather 64ch, norm on the fly, unroll-4 ----------
__global__ __launch_bounds__(256) void gather64_k(const int* __restrict__ row_start,
                                                  const int2* __restrict__ e8,
                                                  const float* __restrict__ dinv,
                                                  const float* __restrict__ h,
                                                  float* __restrict__ agg) {
    const int v = blockIdx.x * 4 + (threadIdx.x >> 6);
    const int lane = threadIdx.x & 63;
    const int i0 = row_start[v], i1 = row_start[v + 1];
    float acc0 = 0.f, acc1 = 0.f, acc2 = 0.f, acc3 = 0.f;
    int i = i0;
    for (; i + 4 <= i1; i += 4) {
        int2 a = e8[i + 0], b = e8[i + 1], c = e8[i + 2], d = e8[i + 3];
        float wa = dinv[a.x] * __int_as_float(a.y);
        float wb = dinv[b.x] * __int_as_float(b.y);
        float wc = dinv[c.x] * __int_as_float(c.y);
        float wd = dinv[d.x] * __int_as_float(d.y);
        acc0 = fmaf(h[(size_t)a.x * HID + lane], wa, acc0);
        acc1 = fmaf(h[(size_t)b.x * HID + lane], wb, acc1);
        acc2 = fmaf(h[(size_t)c.x * HID + lane], wc, acc2);
        acc3 = fmaf(h[(size_t)d.x * HID + lane], wd, acc3);
    }
    for (; i < i1; ++i) {
        int2 a = e8[i];
        acc0 = fmaf(h[(size_t)a.x * HID + lane], dinv[a.x] * __int_as_float(a.y), acc0);
    }
    const float dv = dinv[v];
    float r = dv * ((acc0 + acc1) + (acc2 + acc3));
    r = fmaf(dv * dv, h[(size_t)v * HID + lane], r);
    agg[(size_t)v * HID + lane] = r;
}

// ---------- layer-2 GEMM (fused relu(agg1+b1)) ----------
__global__ __launch_bounds__(256) void gemm2_k(const float* __restrict__ agg1,
                                               const float* __restrict__ b1,
                                               const float* __restrict__ W2,
                                               float* __restrict__ h2) {
    __shared__ float w2s[HID * NC];
    __shared__ float b1s[HID];
    for (int i = threadIdx.x; i < HID * NC; i += 256) w2s[i] = W2[i];
    if (threadIdx.x < HID) b1s[threadIdx.x] = b1[threadIdx.x];
    __syncthreads();

    const int r = blockIdx.x * 256 + threadIdx.x;
    if (r >= NN) return;
    float acc[NC];
#pragma unroll
    for (int c = 0; c < NC; ++c) acc[c] = 0.f;

    const float4* row4 = (const float4*)(agg1 + (size_t)r * HID);
    for (int kk = 0; kk < HID; kk += 4) {
        float4 v = row4[kk >> 2];
        float xr0 = fmaxf(v.x + b1s[kk + 0], 0.f);
        float xr1 = fmaxf(v.y + b1s[kk + 1], 0.f);
        float xr2 = fmaxf(v.z + b1s[kk + 2], 0.f);
        float xr3 = fmaxf(v.w + b1s[kk + 3], 0.f);
#pragma unroll
        for (int c = 0; c < NC; ++c) {
            acc[c] = fmaf(xr0, w2s[(kk + 0) * NC + c], acc[c]);
            acc[c] = fmaf(xr1, w2s[(kk + 1) * NC + c], acc[c]);
            acc[c] = fmaf(xr2, w2s[(kk + 2) * NC + c], acc[c]);
            acc[c] = fmaf(xr3, w2s[(kk + 3) * NC + c], acc[c]);
        }
    }
    float* outp = h2 + (size_t)r * NC;
#pragma unroll
    for (int c = 0; c < NC; c += 4)
        *(float4*)&outp[c] = make_float4(acc[c], acc[c + 1], acc[c + 2], acc[c + 3]);
}

// ---------- gather 40ch + b2 + log_softmax ----------
__global__ __launch_bounds__(256) void gather40_logsm_k(const int* __restrict__ row_start,
                                                        const int2* __restrict__ e8,
                                                        const float* __restrict__ dinv,
                                                        const float* __restrict__ h,
                                                        const float* __restrict__ b2,
                                                        float* __restrict__ out) {
    const int v = blockIdx.x * 4 + (threadIdx.x >> 6);
    const int lane = threadIdx.x & 63;
    const int i0 = row_start[v], i1 = row_start[v + 1];
    const int cl = (lane < NC) ? lane : 0;
    float acc0 = 0.f, acc1 = 0.f, acc2 = 0.f, acc3 = 0.f;
    int i = i0;
    for (; i + 4 <= i1; i += 4) {
        int2 a = e8[i + 0], b = e8[i + 1], c = e8[i + 2], d = e8[i + 3];
        float wa = dinv[a.x] * __int_as_float(a.y);
        float wb = dinv[b.x] * __int_as_float(b.y);
        float wc = dinv[c.x] * __int_as_float(c.y);
        float wd = dinv[d.x] * __int_as_float(d.y);
        acc0 = fmaf(h[(size_t)a.x * NC + cl], wa, acc0);
        acc1 = fmaf(h[(size_t)b.x * NC + cl], wb, acc1);
        acc2 = fmaf(h[(size_t)c.x * NC + cl], wc, acc2);
        acc3 = fmaf(h[(size_t)d.x * NC + cl], wd, acc3);
    }
    for (; i < i1; ++i) {
        int2 a = e8[i];
        acc0 = fmaf(h[(size_t)a.x * NC + cl], dinv[a.x] * __int_as_float(a.y), acc0);
    }
    const float dv = dinv[v];
    float vv = dv * ((acc0 + acc1) + (acc2 + acc3));
    vv = fmaf(dv * dv, h[(size_t)v * NC + cl], vv);
    vv += b2[cl];

    float m = (lane < NC) ? vv : -INFINITY;
#pragma unroll
    for (int off = 32; off >= 1; off >>= 1) m = fmaxf(m, __shfl_xor(m, off, 64));
    float ex = (lane < NC) ? __expf(vv - m) : 0.f;
    float s = ex;
#pragma unroll
    for (int off = 32; off >= 1; off >>= 1) s += __shfl_xor(s, off, 64);
    if (lane < NC) out[(size_t)v * NC + lane] = vv - m - __logf(s);
}

extern "C" void kernel_launch(void* const* d_in, const int* in_sizes, int n_in,
                              void* d_out, int out_size, void* d_ws, size_t ws_size,
                              hipStream_t stream) {
    const float* x  = (const float*)d_in[0];
    const int*   ei = (const int*)d_in[1];     // [2, E]: row0=src, row1=dst
    const float* ea = (const float*)d_in[2];
    const float* W1 = (const float*)d_in[3];
    const float* b1 = (const float*)d_in[4];
    const float* W2 = (const float*)d_in[5];
    const float* b2 = (const float*)d_in[6];
    const int* src = ei;
    const int* dst = ei + NE;
    float* out = (float*)d_out;

    char* ws = (char*)d_ws;
    float* dinv      = (float*)(ws + 0);           //   400,000 B
    int*   cnt       = (int*)  (ws + 400000);      //   400,000 B
    int*   row_start = (int*)  (ws + 800000);      //   400,016 B (NN+1)
    int*   bsum      = (int*)  (ws + 1200128);     //     2,048 B
    int*   boff      = (int*)  (ws + 1202176);     //     2,048 B
    int2*  e8        = (int2*) (ws + 1204224);     // 12,800,000 B
    float* h1        = (float*)(ws + 14004224);    // 25,600,000 B
    float* agg1      = (float*)(ws + 39604224);    // 25,600,000 B -> total 65.2 MB
    int*   rank      = (int*)agg1;                 // 6.4 MB, aliases agg1 (dead before gather64)
    float* h2        = h1;                         // aliases h1 (dead after gather64)

    hipMemsetAsync(cnt, 0, (size_t)NN * sizeof(int), stream);

    fused_gemm1_count_k<<<NG1 * 3, 256, 0, stream>>>(x, W1, h1, dst, cnt, rank);

    scan1_k<<<NB, 256, 0, stream>>>(cnt, bsum);
    scan2_k<<<1, 512, 0, stream>>>(bsum, boff, row_start);
    scan3_k<<<NB, 256, 0, stream>>>(cnt, boff, row_start);
    fill_k <<<NBE, 256, 0, stream>>>(src, dst, ea, rank, row_start, e8);
    degrow_k<<<NN / 4, 256, 0, stream>>>(row_start, e8, dinv);

    gather64_k      <<<NN / 4, 256, 0, stream>>>(row_start, e8, dinv, h1, agg1);
    gemm2_k         <<<(NN + 255) / 256, 256, 0, stream>>>(agg1, b1, W2, h2);
    gather40_logsm_k<<<NN / 4, 256, 0, stream>>>(row_start, e8, dinv, h2, b2, out);
}

// Round 5
// 482.007 us; speedup vs baseline: 2.0744x; 1.0029x over previous
//
#include <hip/hip_runtime.h>
#include <math.h>

#define NN   100000
#define NE   1600000
#define FIN  256
#define HID  64
#define NC   40
#define NBKT 391          // buckets of 256 nodes: bucket = dst >> 8
#define EPB  6250         // edges per phase-A block (256 * 6250 = NE exactly)
#define CAP  4608         // per-bucket capacity (mean 4092, sd 64 -> 8 sigma slack)

// ---------- phase A: partition edges into 391 coarse buckets, coalesced writes ----------
__global__ __launch_bounds__(256) void phaseA_k(const int* __restrict__ src,
                                                const int* __restrict__ dst,
                                                const float* __restrict__ w,
                                                int* __restrict__ cursor,      // [NBKT*16], padded 1/line
                                                int2* __restrict__ bucketbuf) {
    __shared__ int  hist[NBKT];
    __shared__ int  sc[512];
    __shared__ int  loc_base[NBKT];
    __shared__ int  loc_cur[NBKT];
    __shared__ int  gb[NBKT];
    __shared__ int2 buf[EPB];          // 50 KB
    const int t  = threadIdx.x;
    const int e0 = blockIdx.x * EPB;

    for (int i = t; i < NBKT; i += 256) hist[i] = 0;
    __syncthreads();
    // pass 1: histogram by coarse bucket
    for (int i = t; i < EPB; i += 256) atomicAdd(&hist[dst[e0 + i] >> 8], 1);
    __syncthreads();
    // inclusive scan of 512-padded hist (2 elements/thread Hillis-Steele)
    sc[t]       = (t       < NBKT) ? hist[t]       : 0;
    sc[t + 256] = (t + 256 < NBKT) ? hist[t + 256] : 0;
    __syncthreads();
    for (int off = 1; off < 512; off <<= 1) {
        int a0 = (t >= off) ? sc[t - off] : 0;
        int a1 = sc[t + 256 - off];                 // t+256 >= 256 >= off always
        __syncthreads();
        sc[t] += a0; sc[t + 256] += a1;
        __syncthreads();
    }
    // exclusive local bases + reserve global chunks (1 padded atomic per bucket)
    for (int i = t; i < NBKT; i += 256) {
        int base = sc[i] - hist[i];
        loc_base[i] = base;
        loc_cur[i]  = base;
        gb[i] = atomicAdd(&cursor[i * 16], hist[i]);
    }
    __syncthreads();
    // pass 2: scatter into LDS, bucket-sorted
    for (int i = t; i < EPB; i += 256) {
        int e = e0 + i;
        int d = dst[e];
        int b = d >> 8;
        int p = atomicAdd(&loc_cur[b], 1);
        buf[p] = make_int2(src[e] | ((d & 255) << 17), __float_as_int(w[e]));
    }
    __syncthreads();
    // pass 3: coalesced write-out (binary search for slot's bucket)
    for (int i = t; i < EPB; i += 256) {
        int lo = 0, hi = NBKT;
        while (hi - lo > 1) { int mid = (lo + hi) >> 1; if (loc_base[mid] <= i) lo = mid; else hi = mid; }
        bucketbuf[(size_t)lo * CAP + gb[lo] + (i - loc_base[lo])] = buf[i];
    }
}

// ---------- scan of bucket counts -> bucket bases ----------
__global__ __launch_bounds__(512) void scanB_k(const int* __restrict__ cursor,
                                               int* __restrict__ bucketbase,
                                               int* __restrict__ row_start) {
    __shared__ int tmp[512];
    int t = threadIdx.x;
    int v = (t < NBKT) ? cursor[t * 16] : 0;
    tmp[t] = v;
    __syncthreads();
    for (int off = 1; off < 512; off <<= 1) {
        int add = (t >= off) ? tmp[t - off] : 0;
        __syncthreads(); tmp[t] += add; __syncthreads();
    }
    if (t < NBKT) bucketbase[t] = tmp[t] - v;
    if (t == 0) { bucketbase[NBKT] = NE; row_start[NN] = NE; }
}

// ---------- phase B: per-bucket CSR build + row_start + dinv, all coalesced ----------
__global__ __launch_bounds__(256) void phaseB_k(const int* __restrict__ bucketbase,
                                                const int2* __restrict__ bucketbuf,
                                                int2* __restrict__ e8,
                                                int* __restrict__ row_start,
                                                float* __restrict__ dinv) {
    __shared__ int2 buf[CAP];          // 36.9 KB
    __shared__ int2 buf2[CAP];         // 36.9 KB
    __shared__ int  hist2[256];
    __shared__ int  tmp[256];
    __shared__ int  base2[257];
    __shared__ int  cur2[256];
    const int b = blockIdx.x, t = threadIdx.x;
    const int g0   = bucketbase[b];
    const int cntb = bucketbase[b + 1] - g0;
    const int n0   = b * 256;
    const int nnb  = (NN - n0 < 256) ? (NN - n0) : 256;

    hist2[t] = 0;
    __syncthreads();
    const int2* bb = bucketbuf + (size_t)b * CAP;
    for (int i = t; i < cntb; i += 256) {
        int2 kv = bb[i];
        buf[i] = kv;
        atomicAdd(&hist2[kv.x >> 17], 1);
    }
    __syncthreads();
    int v = hist2[t];
    tmp[t] = v;
    __syncthreads();
    for (int off = 1; off < 256; off <<= 1) {
        int add = (t >= off) ? tmp[t - off] : 0;
        __syncthreads(); tmp[t] += add; __syncthreads();
    }
    int excl = tmp[t] - v;
    base2[t] = excl;
    cur2[t]  = excl;
    if (t == 0) base2[256] = cntb;
    if (t < nnb) row_start[n0 + t] = g0 + excl;
    __syncthreads();
    // reorder by node into buf2
    for (int i = t; i < cntb; i += 256) {
        int2 kv = buf[i];
        int d = kv.x >> 17;
        int p = atomicAdd(&cur2[d], 1);
        buf2[p] = make_int2(kv.x & 0x1FFFF, kv.y);
    }
    __syncthreads();
    // coalesced CSR write
    for (int i = t; i < cntb; i += 256) e8[g0 + i] = buf2[i];
    // weighted degree from LDS segments -> dinv
    if (t < nnb) {
        float s = 0.f;
        int j1 = base2[t + 1];
        for (int j = base2[t]; j < j1; ++j) s += __int_as_float(buf2[j].y);
        dinv[n0 + t] = rsqrtf(1.0f + s);
    }
}

// ---------- layer-1 GEMM: h1 = x @ W1 ----------
__global__ __launch_bounds__(256) void gemm1_k(const float* __restrict__ x,
                                               const float* __restrict__ W1,
                                               float* __restrict__ h1) {
    __shared__ float xs[32 * FIN];           // 32 KB
    const int base_row = blockIdx.x * 32;
    const float4* __restrict__ x4 = (const float4*)(x + (size_t)base_row * FIN);
    float4* xs4 = (float4*)xs;
#pragma unroll
    for (int i = 0; i < 8; ++i)
        xs4[threadIdx.x + i * 256] = x4[threadIdx.x + i * 256];
    __syncthreads();

    const int wave = threadIdx.x >> 6;
    const int lane = threadIdx.x & 63;
    const int r0 = wave * 8;
    float acc[8];
#pragma unroll
    for (int j = 0; j < 8; ++j) acc[j] = 0.f;

    for (int kk = 0; kk < FIN; kk += 4) {
        float w0 = W1[(kk + 0) * HID + lane];
        float w1 = W1[(kk + 1) * HID + lane];
        float w2 = W1[(kk + 2) * HID + lane];
        float w3 = W1[(kk + 3) * HID + lane];
#pragma unroll
        for (int j = 0; j < 8; ++j) {
            float4 xq = *(const float4*)&xs[(r0 + j) * FIN + kk];
            acc[j] = fmaf(xq.x, w0, acc[j]);
            acc[j] = fmaf(xq.y, w1, acc[j]);
            acc[j] = fmaf(xq.z, w2, acc[j]);
            acc[j] = fmaf(xq.w, w3, acc[j]);
        }
    }
#pragma unroll
    for (int j = 0; j < 8; ++j)
        h1[(size_t)(base_row + r0 + j) * HID + lane] = acc[j];
}

// ---------- gather 64ch, norm on the fly, unroll-4 ----------
__global__ __launch_bounds__(256) void gather64_k(const int* __restrict__ row_start,
                                                  const int2* __restrict__ e8,
                                                  const float* __restrict__ dinv,
                                                  const float* __restrict__ h,
                                                  float* __restrict__ agg) {
    const int v = blockIdx.x * 4 + (threadIdx.x >> 6);
    const int lane = threadIdx.x & 63;
    const int i0 = row_start[v], i1 = row_start[v + 1];
    float acc0 = 0.f, acc1 = 0.f, acc2 = 0.f, acc3 = 0.f;
    int i = i0;
    for (; i + 4 <= i1; i += 4) {
        int2 a = e8[i + 0], b = e8[i + 1], c = e8[i + 2], d = e8[i + 3];
        float wa = dinv[a.x] * __int_as_float(a.y);
        float wb = dinv[b.x] * __int_as_float(b.y);
        float wc = dinv[c.x] * __int_as_float(c.y);
        float wd = dinv[d.x] * __int_as_float(d.y);
        acc0 = fmaf(h[(size_t)a.x * HID + lane], wa, acc0);
        acc1 = fmaf(h[(size_t)b.x * HID + lane], wb, acc1);
        acc2 = fmaf(h[(size_t)c.x * HID + lane], wc, acc2);
        acc3 = fmaf(h[(size_t)d.x * HID + lane], wd, acc3);
    }
    for (; i < i1; ++i) {
        int2 a = e8[i];
        acc0 = fmaf(h[(size_t)a.x * HID + lane], dinv[a.x] * __int_as_float(a.y), acc0);
    }
    const float dv = dinv[v];
    float r = dv * ((acc0 + acc1) + (acc2 + acc3));
    r = fmaf(dv * dv, h[(size_t)v * HID + lane], r);
    agg[(size_t)v * HID + lane] = r;
}

// ---------- layer-2 GEMM (fused relu(agg1+b1)) ----------
__global__ __launch_bounds__(256) void gemm2_k(const float* __restrict__ agg1,
                                               const float* __restrict__ b1,
                                               const float* __restrict__ W2,
                                               float* __restrict__ h2) {
    __shared__ float w2s[HID * NC];
    __shared__ float b1s[HID];
    for (int i = threadIdx.x; i < HID * NC; i += 256) w2s[i] = W2[i];
    if (threadIdx.x < HID) b1s[threadIdx.x] = b1[threadIdx.x];
    __syncthreads();

    const int r = blockIdx.x * 256 + threadIdx.x;
    if (r >= NN) return;
    float acc[NC];
#pragma unroll
    for (int c = 0; c < NC; ++c) acc[c] = 0.f;

    const float4* row4 = (const float4*)(agg1 + (size_t)r * HID);
    for (int kk = 0; kk < HID; kk += 4) {
        float4 v = row4[kk >> 2];
        float xr0 = fmaxf(v.x + b1s[kk + 0], 0.f);
        float xr1 = fmaxf(v.y + b1s[kk + 1], 0.f);
        float xr2 = fmaxf(v.z + b1s[kk + 2], 0.f);
        float xr3 = fmaxf(v.w + b1s[kk + 3], 0.f);
#pragma unroll
        for (int c = 0; c < NC; ++c) {
            acc[c] = fmaf(xr0, w2s[(kk + 0) * NC + c], acc[c]);
            acc[c] = fmaf(xr1, w2s[(kk + 1) * NC + c], acc[c]);
            acc[c] = fmaf(xr2, w2s[(kk + 2) * NC + c], acc[c]);
            acc[c] = fmaf(xr3, w2s[(kk + 3) * NC + c], acc[c]);
        }
    }
    float* outp = h2 + (size_t)r * NC;
#pragma unroll
    for (int c = 0; c < NC; c += 4)
        *(float4*)&outp[c] = make_float4(acc[c], acc[c + 1], acc[c + 2], acc[c + 3]);
}

// ---------- gather 40ch + b2 + log_softmax ----------
__global__ __launch_bounds__(256) void gather40_logsm_k(const int* __restrict__ row_start,
                                                        const int2* __restrict__ e8,
                                                        const float* __restrict__ dinv,
                                                        const float* __restrict__ h,
                                                        const float* __restrict__ b2,
                                                        float* __restrict__ out) {
    const int v = blockIdx.x * 4 + (threadIdx.x >> 6);
    const int lane = threadIdx.x & 63;
    const int i0 = row_start[v], i1 = row_start[v + 1];
    const int cl = (lane < NC) ? lane : 0;
    float acc0 = 0.f, acc1 = 0.f, acc2 = 0.f, acc3 = 0.f;
    int i = i0;
    for (; i + 4 <= i1; i += 4) {
        int2 a = e8[i + 0], b = e8[i + 1], c = e8[i + 2], d = e8[i + 3];
        float wa = dinv[a.x] * __int_as_float(a.y);
        float wb = dinv[b.x] * __int_as_float(b.y);
        float wc = dinv[c.x] * __int_as_float(c.y);
        float wd = dinv[d.x] * __int_as_float(d.y);
        acc0 = fmaf(h[(size_t)a.x * NC + cl], wa, acc0);
        acc1 = fmaf(h[(size_t)b.x * NC + cl], wb, acc1);
        acc2 = fmaf(h[(size_t)c.x * NC + cl], wc, acc2);
        acc3 = fmaf(h[(size_t)d.x * NC + cl], wd, acc3);
    }
    for (; i < i1; ++i) {
        int2 a = e8[i];
        acc0 = fmaf(h[(size_t)a.x * NC + cl], dinv[a.x] * __int_as_float(a.y), acc0);
    }
    const float dv = dinv[v];
    float vv = dv * ((acc0 + acc1) + (acc2 + acc3));
    vv = fmaf(dv * dv, h[(size_t)v * NC + cl], vv);
    vv += b2[cl];

    float m = (lane < NC) ? vv : -INFINITY;
#pragma unroll
    for (int off = 32; off >= 1; off >>= 1) m = fmaxf(m, __shfl_xor(m, off, 64));
    float ex = (lane < NC) ? __expf(vv - m) : 0.f;
    float s = ex;
#pragma unroll
    for (int off = 32; off >= 1; off >>= 1) s += __shfl_xor(s, off, 64);
    if (lane < NC) out[(size_t)v * NC + lane] = vv - m - __logf(s);
}

extern "C" void kernel_launch(void* const* d_in, const int* in_sizes, int n_in,
                              void* d_out, int out_size, void* d_ws, size_t ws_size,
                              hipStream_t stream) {
    const float* x  = (const float*)d_in[0];
    const int*   ei = (const int*)d_in[1];     // [2, E]: row0=src, row1=dst
    const float* ea = (const float*)d_in[2];
    const float* W1 = (const float*)d_in[3];
    const float* b1 = (const float*)d_in[4];
    const float* W2 = (const float*)d_in[5];
    const float* b2 = (const float*)d_in[6];
    const int* src = ei;
    const int* dst = ei + NE;
    float* out = (float*)d_out;

    char* ws = (char*)d_ws;
    float* dinv       = (float*)(ws + 0);            //    400,000 B
    int*   row_start  = (int*)  (ws + 400000);       //    400,016 B (NN+1)
    int*   cursor     = (int*)  (ws + 800016);       //     25,024 B (391 * 16 ints, line-padded)
    int*   bucketbase = (int*)  (ws + 825040);       //      1,568 B (392)
    int2*  e8         = (int2*) (ws + 826608);       // 12,800,000 B
    float* h1         = (float*)(ws + 13626608);     // 25,600,000 B
    float* agg1       = (float*)(ws + 39226608);     // 25,600,000 B  -> total 64.8 MB
    int2*  bucketbuf  = (int2*)agg1;                 // 14.4 MB, aliases agg1 (dead before gather64)
    float* h2         = h1;                          // aliases h1 (dead after gather64)

    hipMemsetAsync(cursor, 0, 391 * 16 * sizeof(int), stream);

    phaseA_k<<<256,  256, 0, stream>>>(src, dst, ea, cursor, bucketbuf);
    scanB_k <<<1,    512, 0, stream>>>(cursor, bucketbase, row_start);
    phaseB_k<<<NBKT, 256, 0, stream>>>(bucketbase, bucketbuf, e8, row_start, dinv);

    gemm1_k         <<<NN / 32, 256, 0, stream>>>(x, W1, h1);
    gather64_k      <<<NN / 4, 256, 0, stream>>>(row_start, e8, dinv, h1, agg1);
    gemm2_k         <<<(NN + 255) / 256, 256, 0, stream>>>(agg1, b1, W2, h2);
    gather40_logsm_k<<<NN / 4, 256, 0, stream>>>(row_start, e8, dinv, h2, b2, out);
}

// Round 6
// 446.752 us; speedup vs baseline: 2.2381x; 1.0789x over previous
//
#include <hip/hip_runtime.h>
#include <math.h>

#define NN   100000
#define NE   1600000
#define FIN  256
#define HID  64
#define NC   40
#define NBKT 391          // buckets of 256 nodes: bucket = dst >> 8
#define EPB  6250         // edges per phase-A block (256 * 6250 = NE exactly)
#define CAP  4608         // per-bucket capacity (mean 4092, sd 64 -> 8 sigma slack)

typedef __attribute__((ext_vector_type(8))) short short8;
typedef __attribute__((ext_vector_type(4))) float float4v;

static __device__ __forceinline__ short f2bf(float f) {   // RNE f32 -> bf16 bits
    unsigned u = __float_as_uint(f);
    u += 0x7FFFu + ((u >> 16) & 1u);
    return (short)(u >> 16);
}

// ---------- W1 -> bf16, transposed to [n][k] so B-frags are contiguous ----------
__global__ __launch_bounds__(256) void w1cvt_k(const float* __restrict__ W1,
                                               short* __restrict__ w1t) {
    int t = blockIdx.x * 256 + threadIdx.x;   // 16384
    int k = t >> 6, n = t & 63;
    w1t[n * FIN + k] = f2bf(W1[k * HID + n]);
}

// ---------- phase A: partition edges into 391 coarse buckets, coalesced writes ----------
__global__ __launch_bounds__(256) void phaseA_k(const int* __restrict__ src,
                                                const int* __restrict__ dst,
                                                const float* __restrict__ w,
                                                int* __restrict__ cursor,      // [NBKT*16]
                                                int2* __restrict__ bucketbuf) {
    __shared__ int  hist[NBKT];
    __shared__ int  sc[512];
    __shared__ int  loc_base[NBKT];
    __shared__ int  loc_cur[NBKT];
    __shared__ int  gb[NBKT];
    __shared__ int2 buf[EPB];          // 50 KB
    const int t  = threadIdx.x;
    const int e0 = blockIdx.x * EPB;

    for (int i = t; i < NBKT; i += 256) hist[i] = 0;
    __syncthreads();
    for (int i = t; i < EPB; i += 256) atomicAdd(&hist[dst[e0 + i] >> 8], 1);
    __syncthreads();
    sc[t]       = (t       < NBKT) ? hist[t]       : 0;
    sc[t + 256] = (t + 256 < NBKT) ? hist[t + 256] : 0;
    __syncthreads();
    for (int off = 1; off < 512; off <<= 1) {
        int a0 = (t >= off) ? sc[t - off] : 0;
        int a1 = sc[t + 256 - off];
        __syncthreads();
        sc[t] += a0; sc[t + 256] += a1;
        __syncthreads();
    }
    for (int i = t; i < NBKT; i += 256) {
        int base = sc[i] - hist[i];
        loc_base[i] = base;
        loc_cur[i]  = base;
        gb[i] = atomicAdd(&cursor[i * 16], hist[i]);
    }
    __syncthreads();
    for (int i = t; i < EPB; i += 256) {
        int e = e0 + i;
        int d = dst[e];
        int b = d >> 8;
        int p = atomicAdd(&loc_cur[b], 1);
        buf[p] = make_int2(src[e] | ((d & 255) << 17), __float_as_int(w[e]));
    }
    __syncthreads();
    // pass 3: per-bucket sequential copy (no binary search)
    for (int b = t; b < NBKT; b += 256) {
        int lb = loc_base[b], n = hist[b];
        int2* dstp = bucketbuf + (size_t)b * CAP + gb[b];
        for (int i = 0; i < n; ++i) dstp[i] = buf[lb + i];
    }
}

// ---------- scan of bucket counts -> bucket bases ----------
__global__ __launch_bounds__(512) void scanB_k(const int* __restrict__ cursor,
                                               int* __restrict__ bucketbase,
                                               int* __restrict__ row_start) {
    __shared__ int tmp[512];
    int t = threadIdx.x;
    int v = (t < NBKT) ? cursor[t * 16] : 0;
    tmp[t] = v;
    __syncthreads();
    for (int off = 1; off < 512; off <<= 1) {
        int add = (t >= off) ? tmp[t - off] : 0;
        __syncthreads(); tmp[t] += add; __syncthreads();
    }
    if (t < NBKT) bucketbase[t] = tmp[t] - v;
    if (t == 0) { bucketbase[NBKT] = NE; row_start[NN] = NE; }
}

// ---------- phase B: per-bucket CSR build + row_start + dinv, all coalesced ----------
__global__ __launch_bounds__(256) void phaseB_k(const int* __restrict__ bucketbase,
                                                const int2* __restrict__ bucketbuf,
                                                int2* __restrict__ e8,
                                                int* __restrict__ row_start,
                                                float* __restrict__ dinv) {
    __shared__ int2 buf[CAP];
    __shared__ int2 buf2[CAP];
    __shared__ int  hist2[256];
    __shared__ int  tmp[256];
    __shared__ int  base2[257];
    __shared__ int  cur2[256];
    const int b = blockIdx.x, t = threadIdx.x;
    const int g0   = bucketbase[b];
    const int cntb = bucketbase[b + 1] - g0;
    const int n0   = b * 256;
    const int nnb  = (NN - n0 < 256) ? (NN - n0) : 256;

    hist2[t] = 0;
    __syncthreads();
    const int2* bb = bucketbuf + (size_t)b * CAP;
    for (int i = t; i < cntb; i += 256) {
        int2 kv = bb[i];
        buf[i] = kv;
        atomicAdd(&hist2[kv.x >> 17], 1);
    }
    __syncthreads();
    int v = hist2[t];
    tmp[t] = v;
    __syncthreads();
    for (int off = 1; off < 256; off <<= 1) {
        int add = (t >= off) ? tmp[t - off] : 0;
        __syncthreads(); tmp[t] += add; __syncthreads();
    }
    int excl = tmp[t] - v;
    base2[t] = excl;
    cur2[t]  = excl;
    if (t == 0) base2[256] = cntb;
    if (t < nnb) row_start[n0 + t] = g0 + excl;
    __syncthreads();
    for (int i = t; i < cntb; i += 256) {
        int2 kv = buf[i];
        int d = kv.x >> 17;
        int p = atomicAdd(&cur2[d], 1);
        buf2[p] = make_int2(kv.x & 0x1FFFF, kv.y);
    }
    __syncthreads();
    for (int i = t; i < cntb; i += 256) e8[g0 + i] = buf2[i];
    if (t < nnb) {
        float s = 0.f;
        int j1 = base2[t + 1];
        for (int j = base2[t]; j < j1; ++j) s += __int_as_float(buf2[j].y);
        dinv[n0 + t] = rsqrtf(1.0f + s);
    }
}

// ---------- layer-1 GEMM via MFMA bf16: h1 = x @ W1 ----------
// block = 4 waves; wave computes 16 rows x 64 cols; K = 256 in 8 chunks of 32.
__global__ __launch_bounds__(256) void gemm1_mfma_k(const float* __restrict__ x,
                                                    const short* __restrict__ w1t,  // bf16 [64][256]
                                                    float* __restrict__ h1) {
    const int wave = threadIdx.x >> 6;
    const int lane = threadIdx.x & 63;
    const int m    = lane & 15;
    const int quad = lane >> 4;
    const int r0   = blockIdx.x * 64 + wave * 16;
    const int row  = r0 + m;
    const int rcl  = (row < NN) ? row : (NN - 1);
    const float* xrow = x + (size_t)rcl * FIN + quad * 8;

    float4v acc0 = {0.f,0.f,0.f,0.f}, acc1 = acc0, acc2 = acc0, acc3 = acc0;

#pragma unroll
    for (int kc = 0; kc < 8; ++kc) {
        const int kof = kc * 32 + quad * 8;
        float4 xa = *(const float4*)(xrow + kc * 32);
        float4 xb = *(const float4*)(xrow + kc * 32 + 4);
        short8 a;
        a[0] = f2bf(xa.x); a[1] = f2bf(xa.y); a[2] = f2bf(xa.z); a[3] = f2bf(xa.w);
        a[4] = f2bf(xb.x); a[5] = f2bf(xb.y); a[6] = f2bf(xb.z); a[7] = f2bf(xb.w);
        short8 b0 = *(const short8*)(w1t + (0 * 16 + m) * FIN + kof);
        short8 b1 = *(const short8*)(w1t + (1 * 16 + m) * FIN + kof);
        short8 b2 = *(const short8*)(w1t + (2 * 16 + m) * FIN + kof);
        short8 b3 = *(const short8*)(w1t + (3 * 16 + m) * FIN + kof);
        acc0 = __builtin_amdgcn_mfma_f32_16x16x32_bf16(a, b0, acc0, 0, 0, 0);
        acc1 = __builtin_amdgcn_mfma_f32_16x16x32_bf16(a, b1, acc1, 0, 0, 0);
        acc2 = __builtin_amdgcn_mfma_f32_16x16x32_bf16(a, b2, acc2, 0, 0, 0);
        acc3 = __builtin_amdgcn_mfma_f32_16x16x32_bf16(a, b3, acc3, 0, 0, 0);
    }
    // C/D layout: col = lane&15, row = quad*4 + reg
#pragma unroll
    for (int r = 0; r < 4; ++r) {
        int rr = r0 + quad * 4 + r;
        if (rr < NN) {
            float* hp = h1 + (size_t)rr * HID + m;
            hp[0]  = acc0[r];
            hp[16] = acc1[r];
            hp[32] = acc2[r];
            hp[48] = acc3[r];
        }
    }
}

// ---------- gather 64ch, norm on the fly, unroll-4 ----------
__global__ __launch_bounds__(256) void gather64_k(const int* __restrict__ row_start,
                                                  const int2* __restrict__ e8,
                                                  const float* __restrict__ dinv,
                                                  const float* __restrict__ h,
                                                  float* __restrict__ agg) {
    const int v = blockIdx.x * 4 + (threadIdx.x >> 6);
    const int lane = threadIdx.x & 63;
    const int i0 = row_start[v], i1 = row_start[v + 1];
    float acc0 = 0.f, acc1 = 0.f, acc2 = 0.f, acc3 = 0.f;
    int i = i0;
    for (; i + 4 <= i1; i += 4) {
        int2 a = e8[i + 0], b = e8[i + 1], c = e8[i + 2], d = e8[i + 3];
        float wa = dinv[a.x] * __int_as_float(a.y);
        float wb = dinv[b.x] * __int_as_float(b.y);
        float wc = dinv[c.x] * __int_as_float(c.y);
        float wd = dinv[d.x] * __int_as_float(d.y);
        acc0 = fmaf(h[(size_t)a.x * HID + lane], wa, acc0);
        acc1 = fmaf(h[(size_t)b.x * HID + lane], wb, acc1);
        acc2 = fmaf(h[(size_t)c.x * HID + lane], wc, acc2);
        acc3 = fmaf(h[(size_t)d.x * HID + lane], wd, acc3);
    }
    for (; i < i1; ++i) {
        int2 a = e8[i];
        acc0 = fmaf(h[(size_t)a.x * HID + lane], dinv[a.x] * __int_as_float(a.y), acc0);
    }
    const float dv = dinv[v];
    float r = dv * ((acc0 + acc1) + (acc2 + acc3));
    r = fmaf(dv * dv, h[(size_t)v * HID + lane], r);
    agg[(size_t)v * HID + lane] = r;
}

// ---------- layer-2 GEMM (fused relu(agg1+b1)) ----------
__global__ __launch_bounds__(256) void gemm2_k(const float* __restrict__ agg1,
                                               const float* __restrict__ b1,
                                               const float* __restrict__ W2,
                                               float* __restrict__ h2) {
    __shared__ float w2s[HID * NC];
    __shared__ float b1s[HID];
    for (int i = threadIdx.x; i < HID * NC; i += 256) w2s[i] = W2[i];
    if (threadIdx.x < HID) b1s[threadIdx.x] = b1[threadIdx.x];
    __syncthreads();

    const int r = blockIdx.x * 256 + threadIdx.x;
    if (r >= NN) return;
    float acc[NC];
#pragma unroll
    for (int c = 0; c < NC; ++c) acc[c] = 0.f;

    const float4* row4 = (const float4*)(agg1 + (size_t)r * HID);
    for (int kk = 0; kk < HID; kk += 4) {
        float4 v = row4[kk >> 2];
        float xr0 = fmaxf(v.x + b1s[kk + 0], 0.f);
        float xr1 = fmaxf(v.y + b1s[kk + 1], 0.f);
        float xr2 = fmaxf(v.z + b1s[kk + 2], 0.f);
        float xr3 = fmaxf(v.w + b1s[kk + 3], 0.f);
#pragma unroll
        for (int c = 0; c < NC; ++c) {
            acc[c] = fmaf(xr0, w2s[(kk + 0) * NC + c], acc[c]);
            acc[c] = fmaf(xr1, w2s[(kk + 1) * NC + c], acc[c]);
            acc[c] = fmaf(xr2, w2s[(kk + 2) * NC + c], acc[c]);
            acc[c] = fmaf(xr3, w2s[(kk + 3) * NC + c], acc[c]);
        }
    }
    float* outp = h2 + (size_t)r * NC;
#pragma unroll
    for (int c = 0; c < NC; c += 4)
        *(float4*)&outp[c] = make_float4(acc[c], acc[c + 1], acc[c + 2], acc[c + 3]);
}

// ---------- gather 40ch + b2 + log_softmax ----------
__global__ __launch_bounds__(256) void gather40_logsm_k(const int* __restrict__ row_start,
                                                        const int2* __restrict__ e8,
                                                        const float* __restrict__ dinv,
                                                        const float* __restrict__ h,
                                                        const float* __restrict__ b2,
                                                        float* __restrict__ out) {
    const int v = blockIdx.x * 4 + (threadIdx.x >> 6);
    const int lane = threadIdx.x & 63;
    const int i0 = row_start[v], i1 = row_start[v + 1];
    const int cl = (lane < NC) ? lane : 0;
    float acc0 = 0.f, acc1 = 0.f, acc2 = 0.f, acc3 = 0.f;
    int i = i0;
    for (; i + 4 <= i1; i += 4) {
        int2 a = e8[i + 0], b = e8[i + 1], c = e8[i + 2], d = e8[i + 3];
        float wa = dinv[a.x] * __int_as_float(a.y);
        float wb = dinv[b.x] * __int_as_float(b.y);
        float wc = dinv[c.x] * __int_as_float(c.y);
        float wd = dinv[d.x] * __int_as_float(d.y);
        acc0 = fmaf(h[(size_t)a.x * NC + cl], wa, acc0);
        acc1 = fmaf(h[(size_t)b.x * NC + cl], wb, acc1);
        acc2 = fmaf(h[(size_t)c.x * NC + cl], wc, acc2);
        acc3 = fmaf(h[(size_t)d.x * NC + cl], wd, acc3);
    }
    for (; i < i1; ++i) {
        int2 a = e8[i];
        acc0 = fmaf(h[(size_t)a.x * NC + cl], dinv[a.x] * __int_as_float(a.y), acc0);
    }
    const float dv = dinv[v];
    float vv = dv * ((acc0 + acc1) + (acc2 + acc3));
    vv = fmaf(dv * dv, h[(size_t)v * NC + cl], vv);
    vv += b2[cl];

    float m = (lane < NC) ? vv : -INFINITY;
#pragma unroll
    for (int off = 32; off >= 1; off >>= 1) m = fmaxf(m, __shfl_xor(m, off, 64));
    float ex = (lane < NC) ? __expf(vv - m) : 0.f;
    float s = ex;
#pragma unroll
    for (int off = 32; off >= 1; off >>= 1) s += __shfl_xor(s, off, 64);
    if (lane < NC) out[(size_t)v * NC + lane] = vv - m - __logf(s);
}

extern "C" void kernel_launch(void* const* d_in, const int* in_sizes, int n_in,
                              void* d_out, int out_size, void* d_ws, size_t ws_size,
                              hipStream_t stream) {
    const float* x  = (const float*)d_in[0];
    const int*   ei = (const int*)d_in[1];     // [2, E]: row0=src, row1=dst
    const float* ea = (const float*)d_in[2];
    const float* W1 = (const float*)d_in[3];
    const float* b1 = (const float*)d_in[4];
    const float* W2 = (const float*)d_in[5];
    const float* b2 = (const float*)d_in[6];
    const int* src = ei;
    const int* dst = ei + NE;
    float* out = (float*)d_out;

    char* ws = (char*)d_ws;
    float* dinv       = (float*)(ws + 0);            //    400,000 B
    int*   row_start  = (int*)  (ws + 400000);       //    400,016 B (NN+1)
    int*   cursor     = (int*)  (ws + 800016);       //     25,024 B (391*16, line-padded)
    int*   bucketbase = (int*)  (ws + 825040);       //      1,568 B
    int2*  e8         = (int2*) (ws + 826608);       // 12,800,000 B
    float* h1         = (float*)(ws + 13626608);     // 25,600,000 B
    float* agg1       = (float*)(ws + 39226608);     // 25,600,000 B
    short* w1t        = (short*)(ws + 64826608);     //     32,768 B -> total 64.86 MB
    int2*  bucketbuf  = (int2*)agg1;                 // 14.4 MB, aliases agg1 (dead before gather64)
    float* h2         = h1;                          // aliases h1 (dead after gather64)

    hipMemsetAsync(cursor, 0, 391 * 16 * sizeof(int), stream);

    w1cvt_k <<<64,   256, 0, stream>>>(W1, w1t);
    phaseA_k<<<256,  256, 0, stream>>>(src, dst, ea, cursor, bucketbuf);
    scanB_k <<<1,    512, 0, stream>>>(cursor, bucketbase, row_start);
    phaseB_k<<<NBKT, 256, 0, stream>>>(bucketbase, bucketbuf, e8, row_start, dinv);

    gemm1_mfma_k    <<<(NN + 63) / 64, 256, 0, stream>>>(x, w1t, h1);
    gather64_k      <<<NN / 4, 256, 0, stream>>>(row_start, e8, dinv, h1, agg1);
    gemm2_k         <<<(NN + 255) / 256, 256, 0, stream>>>(agg1, b1, W2, h2);
    gather40_logsm_k<<<NN / 4, 256, 0, stream>>>(row_start, e8, dinv, h2, b2, out);
}

// Round 7
// 431.605 us; speedup vs baseline: 2.3166x; 1.0351x over previous
//
#include <hip/hip_runtime.h>
#include <math.h>

#define NN   100000
#define NE   1600000
#define FIN  256
#define HID  64
#define NC   40
#define NBKT 391          // buckets of 256 nodes: bucket = dst >> 8
#define EPB  6250         // edges per phase-A block (256 * 6250 = NE exactly)
#define CAP  4608         // per-bucket capacity (mean 4092, sd 64 -> 8 sigma slack)

typedef __attribute__((ext_vector_type(8))) short short8;
typedef __attribute__((ext_vector_type(4))) float float4v;

static __device__ __forceinline__ short f2bf(float f) {   // RNE f32 -> bf16 bits
    unsigned u = __float_as_uint(f);
    u += 0x7FFFu + ((u >> 16) & 1u);
    return (short)(u >> 16);
}
static __device__ __forceinline__ float bf2f(unsigned short b) {
    return __uint_as_float((unsigned)b << 16);
}

// ---------- W1 -> bf16, transposed to [n][k] so B-frags are contiguous ----------
__global__ __launch_bounds__(256) void w1cvt_k(const float* __restrict__ W1,
                                               short* __restrict__ w1t) {
    int t = blockIdx.x * 256 + threadIdx.x;   // 16384
    int k = t >> 6, n = t & 63;
    w1t[n * FIN + k] = f2bf(W1[k * HID + n]);
}

// ---------- phase A: partition edges into 391 coarse buckets, coalesced writes ----------
__global__ __launch_bounds__(256) void phaseA_k(const int* __restrict__ src,
                                                const int* __restrict__ dst,
                                                const float* __restrict__ w,
                                                int* __restrict__ cursor,      // [NBKT*16]
                                                int2* __restrict__ bucketbuf) {
    __shared__ int  hist[NBKT];
    __shared__ int  sc[512];
    __shared__ int  loc_base[NBKT];
    __shared__ int  loc_cur[NBKT];
    __shared__ int  gb[NBKT];
    __shared__ int2 buf[EPB];          // 50 KB
    const int t  = threadIdx.x;
    const int e0 = blockIdx.x * EPB;

    for (int i = t; i < NBKT; i += 256) hist[i] = 0;
    __syncthreads();
    for (int i = t; i < EPB; i += 256) atomicAdd(&hist[dst[e0 + i] >> 8], 1);
    __syncthreads();
    sc[t]       = (t       < NBKT) ? hist[t]       : 0;
    sc[t + 256] = (t + 256 < NBKT) ? hist[t + 256] : 0;
    __syncthreads();
    for (int off = 1; off < 512; off <<= 1) {
        int a0 = (t >= off) ? sc[t - off] : 0;
        int a1 = sc[t + 256 - off];
        __syncthreads();
        sc[t] += a0; sc[t + 256] += a1;
        __syncthreads();
    }
    for (int i = t; i < NBKT; i += 256) {
        int base = sc[i] - hist[i];
        loc_base[i] = base;
        loc_cur[i]  = base;
        gb[i] = atomicAdd(&cursor[i * 16], hist[i]);
    }
    __syncthreads();
    for (int i = t; i < EPB; i += 256) {
        int e = e0 + i;
        int d = dst[e];
        int b = d >> 8;
        int p = atomicAdd(&loc_cur[b], 1);
        buf[p] = make_int2(src[e] | ((d & 255) << 17), __float_as_int(w[e]));
    }
    __syncthreads();
    // pass 3: per-bucket sequential copy
    for (int b = t; b < NBKT; b += 256) {
        int lb = loc_base[b], n = hist[b];
        int2* dstp = bucketbuf + (size_t)b * CAP + gb[b];
        for (int i = 0; i < n; ++i) dstp[i] = buf[lb + i];
    }
}

// ---------- scan of bucket counts -> bucket bases ----------
__global__ __launch_bounds__(512) void scanB_k(const int* __restrict__ cursor,
                                               int* __restrict__ bucketbase,
                                               int* __restrict__ row_start) {
    __shared__ int tmp[512];
    int t = threadIdx.x;
    int v = (t < NBKT) ? cursor[t * 16] : 0;
    tmp[t] = v;
    __syncthreads();
    for (int off = 1; off < 512; off <<= 1) {
        int add = (t >= off) ? tmp[t - off] : 0;
        __syncthreads(); tmp[t] += add; __syncthreads();
    }
    if (t < NBKT) bucketbase[t] = tmp[t] - v;
    if (t == 0) { bucketbase[NBKT] = NE; row_start[NN] = NE; }
}

// ---------- phase B: per-bucket CSR build + row_start + dinv ----------
__global__ __launch_bounds__(256) void phaseB_k(const int* __restrict__ bucketbase,
                                                const int2* __restrict__ bucketbuf,
                                                int2* __restrict__ e8,
                                                int* __restrict__ row_start,
                                                float* __restrict__ dinv) {
    __shared__ int2 buf[CAP];
    __shared__ int2 buf2[CAP];
    __shared__ int  hist2[256];
    __shared__ int  tmp[256];
    __shared__ int  base2[257];
    __shared__ int  cur2[256];
    const int b = blockIdx.x, t = threadIdx.x;
    const int g0   = bucketbase[b];
    const int cntb = bucketbase[b + 1] - g0;
    const int n0   = b * 256;
    const int nnb  = (NN - n0 < 256) ? (NN - n0) : 256;

    hist2[t] = 0;
    __syncthreads();
    const int2* bb = bucketbuf + (size_t)b * CAP;
    for (int i = t; i < cntb; i += 256) {
        int2 kv = bb[i];
        buf[i] = kv;
        atomicAdd(&hist2[kv.x >> 17], 1);
    }
    __syncthreads();
    int v = hist2[t];
    tmp[t] = v;
    __syncthreads();
    for (int off = 1; off < 256; off <<= 1) {
        int add = (t >= off) ? tmp[t - off] : 0;
        __syncthreads(); tmp[t] += add; __syncthreads();
    }
    int excl = tmp[t] - v;
    base2[t] = excl;
    cur2[t]  = excl;
    if (t == 0) base2[256] = cntb;
    if (t < nnb) row_start[n0 + t] = g0 + excl;
    __syncthreads();
    for (int i = t; i < cntb; i += 256) {
        int2 kv = buf[i];
        int d = kv.x >> 17;
        int p = atomicAdd(&cur2[d], 1);
        buf2[p] = make_int2(kv.x & 0x1FFFF, kv.y);
    }
    __syncthreads();
    for (int i = t; i < cntb; i += 256) e8[g0 + i] = buf2[i];
    if (t < nnb) {
        float s = 0.f;
        int j1 = base2[t + 1];
        for (int j = base2[t]; j < j1; ++j) s += __int_as_float(buf2[j].y);
        dinv[n0 + t] = rsqrtf(1.0f + s);
    }
}

// ---------- layer-1 GEMM via MFMA bf16: h1(bf16) = x @ W1 ----------
__global__ __launch_bounds__(256) void gemm1_mfma_k(const float* __restrict__ x,
                                                    const short* __restrict__ w1t,  // bf16 [64][256]
                                                    unsigned short* __restrict__ h1) {
    const int wave = threadIdx.x >> 6;
    const int lane = threadIdx.x & 63;
    const int m    = lane & 15;
    const int quad = lane >> 4;
    const int r0   = blockIdx.x * 64 + wave * 16;
    const int row  = r0 + m;
    const int rcl  = (row < NN) ? row : (NN - 1);
    const float* xrow = x + (size_t)rcl * FIN + quad * 8;

    float4v acc0 = {0.f,0.f,0.f,0.f}, acc1 = acc0, acc2 = acc0, acc3 = acc0;

#pragma unroll
    for (int kc = 0; kc < 8; ++kc) {
        const int kof = kc * 32 + quad * 8;
        float4 xa = *(const float4*)(xrow + kc * 32);
        float4 xb = *(const float4*)(xrow + kc * 32 + 4);
        short8 a;
        a[0] = f2bf(xa.x); a[1] = f2bf(xa.y); a[2] = f2bf(xa.z); a[3] = f2bf(xa.w);
        a[4] = f2bf(xb.x); a[5] = f2bf(xb.y); a[6] = f2bf(xb.z); a[7] = f2bf(xb.w);
        short8 b0 = *(const short8*)(w1t + (0 * 16 + m) * FIN + kof);
        short8 b1 = *(const short8*)(w1t + (1 * 16 + m) * FIN + kof);
        short8 b2 = *(const short8*)(w1t + (2 * 16 + m) * FIN + kof);
        short8 b3 = *(const short8*)(w1t + (3 * 16 + m) * FIN + kof);
        acc0 = __builtin_amdgcn_mfma_f32_16x16x32_bf16(a, b0, acc0, 0, 0, 0);
        acc1 = __builtin_amdgcn_mfma_f32_16x16x32_bf16(a, b1, acc1, 0, 0, 0);
        acc2 = __builtin_amdgcn_mfma_f32_16x16x32_bf16(a, b2, acc2, 0, 0, 0);
        acc3 = __builtin_amdgcn_mfma_f32_16x16x32_bf16(a, b3, acc3, 0, 0, 0);
    }
    // C/D layout: col = lane&15, row = quad*4 + reg
#pragma unroll
    for (int r = 0; r < 4; ++r) {
        int rr = r0 + quad * 4 + r;
        if (rr < NN) {
            unsigned short* hp = h1 + (size_t)rr * HID + m;
            hp[0]  = (unsigned short)f2bf(acc0[r]);
            hp[16] = (unsigned short)f2bf(acc1[r]);
            hp[32] = (unsigned short)f2bf(acc2[r]);
            hp[48] = (unsigned short)f2bf(acc3[r]);
        }
    }
}

// ---------- gather 64ch from bf16 h, fp32 accumulate ----------
__global__ __launch_bounds__(256) void gather64_k(const int* __restrict__ row_start,
                                                  const int2* __restrict__ e8,
                                                  const float* __restrict__ dinv,
                                                  const unsigned short* __restrict__ h,
                                                  float* __restrict__ agg) {
    const int v = blockIdx.x * 4 + (threadIdx.x >> 6);
    const int lane = threadIdx.x & 63;
    const int i0 = row_start[v], i1 = row_start[v + 1];
    float acc0 = 0.f, acc1 = 0.f, acc2 = 0.f, acc3 = 0.f;
    int i = i0;
    for (; i + 4 <= i1; i += 4) {
        int2 a = e8[i + 0], b = e8[i + 1], c = e8[i + 2], d = e8[i + 3];
        float wa = dinv[a.x] * __int_as_float(a.y);
        float wb = dinv[b.x] * __int_as_float(b.y);
        float wc = dinv[c.x] * __int_as_float(c.y);
        float wd = dinv[d.x] * __int_as_float(d.y);
        acc0 = fmaf(bf2f(h[(size_t)a.x * HID + lane]), wa, acc0);
        acc1 = fmaf(bf2f(h[(size_t)b.x * HID + lane]), wb, acc1);
        acc2 = fmaf(bf2f(h[(size_t)c.x * HID + lane]), wc, acc2);
        acc3 = fmaf(bf2f(h[(size_t)d.x * HID + lane]), wd, acc3);
    }
    for (; i < i1; ++i) {
        int2 a = e8[i];
        acc0 = fmaf(bf2f(h[(size_t)a.x * HID + lane]), dinv[a.x] * __int_as_float(a.y), acc0);
    }
    const float dv = dinv[v];
    float r = dv * ((acc0 + acc1) + (acc2 + acc3));
    r = fmaf(dv * dv, bf2f(h[(size_t)v * HID + lane]), r);
    agg[(size_t)v * HID + lane] = r;
}

// ---------- layer-2 GEMM (fused relu(agg1+b1)), bf16 h2 out ----------
__global__ __launch_bounds__(256) void gemm2_k(const float* __restrict__ agg1,
                                               const float* __restrict__ b1,
                                               const float* __restrict__ W2,
                                               unsigned short* __restrict__ h2) {
    __shared__ float w2s[HID * NC];
    __shared__ float b1s[HID];
    for (int i = threadIdx.x; i < HID * NC; i += 256) w2s[i] = W2[i];
    if (threadIdx.x < HID) b1s[threadIdx.x] = b1[threadIdx.x];
    __syncthreads();

    const int r = blockIdx.x * 256 + threadIdx.x;
    if (r >= NN) return;
    float acc[NC];
#pragma unroll
    for (int c = 0; c < NC; ++c) acc[c] = 0.f;

    const float4* row4 = (const float4*)(agg1 + (size_t)r * HID);
    for (int kk = 0; kk < HID; kk += 4) {
        float4 v = row4[kk >> 2];
        float xr0 = fmaxf(v.x + b1s[kk + 0], 0.f);
        float xr1 = fmaxf(v.y + b1s[kk + 1], 0.f);
        float xr2 = fmaxf(v.z + b1s[kk + 2], 0.f);
        float xr3 = fmaxf(v.w + b1s[kk + 3], 0.f);
#pragma unroll
        for (int c = 0; c < NC; ++c) {
            acc[c] = fmaf(xr0, w2s[(kk + 0) * NC + c], acc[c]);
            acc[c] = fmaf(xr1, w2s[(kk + 1) * NC + c], acc[c]);
            acc[c] = fmaf(xr2, w2s[(kk + 2) * NC + c], acc[c]);
            acc[c] = fmaf(xr3, w2s[(kk + 3) * NC + c], acc[c]);
        }
    }
    unsigned short* outp = h2 + (size_t)r * NC;
    ushort2* o2 = (ushort2*)outp;
#pragma unroll
    for (int c = 0; c < NC; c += 2)
        o2[c >> 1] = make_ushort2((unsigned short)f2bf(acc[c]), (unsigned short)f2bf(acc[c + 1]));
}

// ---------- gather 40ch from bf16 h2 + b2 + log_softmax ----------
__global__ __launch_bounds__(256) void gather40_logsm_k(const int* __restrict__ row_start,
                                                        const int2* __restrict__ e8,
                                                        const float* __restrict__ dinv,
                                                        const unsigned short* __restrict__ h,
                                                        const float* __restrict__ b2,
                                                        float* __restrict__ out) {
    const int v = blockIdx.x * 4 + (threadIdx.x >> 6);
    const int lane = threadIdx.x & 63;
    const int i0 = row_start[v], i1 = row_start[v + 1];
    const int cl = (lane < NC) ? lane : 0;
    float acc0 = 0.f, acc1 = 0.f, acc2 = 0.f, acc3 = 0.f;
    int i = i0;
    for (; i + 4 <= i1; i += 4) {
        int2 a = e8[i + 0], b = e8[i + 1], c = e8[i + 2], d = e8[i + 3];
        float wa = dinv[a.x] * __int_as_float(a.y);
        float wb = dinv[b.x] * __int_as_float(b.y);
        float wc = dinv[c.x] * __int_as_float(c.y);
        float wd = dinv[d.x] * __int_as_float(d.y);
        acc0 = fmaf(bf2f(h[(size_t)a.x * NC + cl]), wa, acc0);
        acc1 = fmaf(bf2f(h[(size_t)b.x * NC + cl]), wb, acc1);
        acc2 = fmaf(bf2f(h[(size_t)c.x * NC + cl]), wc, acc2);
        acc3 = fmaf(bf2f(h[(size_t)d.x * NC + cl]), wd, acc3);
    }
    for (; i < i1; ++i) {
        int2 a = e8[i];
        acc0 = fmaf(bf2f(h[(size_t)a.x * NC + cl]), dinv[a.x] * __int_as_float(a.y), acc0);
    }
    const float dv = dinv[v];
    float vv = dv * ((acc0 + acc1) + (acc2 + acc3));
    vv = fmaf(dv * dv, bf2f(h[(size_t)v * NC + cl]), vv);
    vv += b2[cl];

    float m = (lane < NC) ? vv : -INFINITY;
#pragma unroll
    for (int off = 32; off >= 1; off >>= 1) m = fmaxf(m, __shfl_xor(m, off, 64));
    float ex = (lane < NC) ? __expf(vv - m) : 0.f;
    float s = ex;
#pragma unroll
    for (int off = 32; off >= 1; off >>= 1) s += __shfl_xor(s, off, 64);
    if (lane < NC) out[(size_t)v * NC + lane] = vv - m - __logf(s);
}

extern "C" void kernel_launch(void* const* d_in, const int* in_sizes, int n_in,
                              void* d_out, int out_size, void* d_ws, size_t ws_size,
                              hipStream_t stream) {
    const float* x  = (const float*)d_in[0];
    const int*   ei = (const int*)d_in[1];     // [2, E]: row0=src, row1=dst
    const float* ea = (const float*)d_in[2];
    const float* W1 = (const float*)d_in[3];
    const float* b1 = (const float*)d_in[4];
    const float* W2 = (const float*)d_in[5];
    const float* b2 = (const float*)d_in[6];
    const int* src = ei;
    const int* dst = ei + NE;
    float* out = (float*)d_out;

    char* ws = (char*)d_ws;
    float* dinv       = (float*)(ws + 0);            //    400,000 B
    int*   row_start  = (int*)  (ws + 400000);       //    400,016 B (NN+1)
    int*   cursor     = (int*)  (ws + 800016);       //     25,024 B (391*16, line-padded)
    int*   bucketbase = (int*)  (ws + 825040);       //      1,568 B
    int2*  e8         = (int2*) (ws + 826608);       // 12,800,000 B
    unsigned short* h1 = (unsigned short*)(ws + 13626608);   // 12,800,000 B (bf16)
    float* agg1       = (float*)(ws + 26426608);     // 25,600,000 B
    short* w1t        = (short*)(ws + 52026608);     //     32,768 B -> total 52.06 MB
    int2*  bucketbuf  = (int2*)agg1;                 // 14.4 MB, aliases agg1 (dead before gather64)
    unsigned short* h2 = h1;                         // aliases h1 (dead after gather64; 8 MB <= 12.8 MB)

    hipMemsetAsync(cursor, 0, 391 * 16 * sizeof(int), stream);

    w1cvt_k <<<64,   256, 0, stream>>>(W1, w1t);
    phaseA_k<<<256,  256, 0, stream>>>(src, dst, ea, cursor, bucketbuf);
    scanB_k <<<1,    512, 0, stream>>>(cursor, bucketbase, row_start);
    phaseB_k<<<NBKT, 256, 0, stream>>>(bucketbase, bucketbuf, e8, row_start, dinv);

    gemm1_mfma_k    <<<(NN + 63) / 64, 256, 0, stream>>>(x, w1t, h1);
    gather64_k      <<<NN / 4, 256, 0, stream>>>(row_start, e8, dinv, h1, agg1);
    gemm2_k         <<<(NN + 255) / 256, 256, 0, stream>>>(agg1, b1, W2, h2);
    gather40_logsm_k<<<NN / 4, 256, 0, stream>>>(row_start, e8, dinv, h2, b2, out);
}

// Round 8
// 419.883 us; speedup vs baseline: 2.3813x; 1.0279x over previous
//
#include <hip/hip_runtime.h>
#include <math.h>

#define NN   100000
#define NE   1600000
#define FIN  256
#define HID  64
#define NC   40
#define NBKT 391          // buckets of 256 nodes: bucket = dst >> 8
#define EPB  6250         // edges per phase-A block (256 * 6250 = NE exactly)
#define CAP  4608         // per-bucket capacity (mean 4092, sd 64 -> 8 sigma slack)

typedef __attribute__((ext_vector_type(8))) short short8;
typedef __attribute__((ext_vector_type(4))) float float4v;

static __device__ __forceinline__ short f2bf(float f) {   // RNE f32 -> bf16 bits
    unsigned u = __float_as_uint(f);
    u += 0x7FFFu + ((u >> 16) & 1u);
    return (short)(u >> 16);
}
static __device__ __forceinline__ float bf2f(unsigned short b) {
    return __uint_as_float((unsigned)b << 16);
}

// ---------- W1 -> bf16, transposed to [n][k] ----------
__global__ __launch_bounds__(256) void w1cvt_k(const float* __restrict__ W1,
                                               short* __restrict__ w1t) {
    int t = blockIdx.x * 256 + threadIdx.x;   // 16384
    int k = t >> 6, n = t & 63;
    w1t[n * FIN + k] = f2bf(W1[k * HID + n]);
}

// ---------- phase A: partition edges into 391 coarse buckets ----------
__global__ __launch_bounds__(256) void phaseA_k(const int* __restrict__ src,
                                                const int* __restrict__ dst,
                                                const float* __restrict__ w,
                                                int* __restrict__ cursor,      // [NBKT*16]
                                                int2* __restrict__ bucketbuf) {
    __shared__ int  hist[NBKT];
    __shared__ int  sc[512];
    __shared__ int  loc_base[NBKT];
    __shared__ int  loc_cur[NBKT];
    __shared__ int  gb[NBKT];
    __shared__ int2 buf[EPB];          // 50 KB
    const int t  = threadIdx.x;
    const int e0 = blockIdx.x * EPB;

    for (int i = t; i < NBKT; i += 256) hist[i] = 0;
    __syncthreads();
    for (int i = t; i < EPB; i += 256) atomicAdd(&hist[dst[e0 + i] >> 8], 1);
    __syncthreads();
    sc[t]       = (t       < NBKT) ? hist[t]       : 0;
    sc[t + 256] = (t + 256 < NBKT) ? hist[t + 256] : 0;
    __syncthreads();
    for (int off = 1; off < 512; off <<= 1) {
        int a0 = (t >= off) ? sc[t - off] : 0;
        int a1 = sc[t + 256 - off];
        __syncthreads();
        sc[t] += a0; sc[t + 256] += a1;
        __syncthreads();
    }
    for (int i = t; i < NBKT; i += 256) {
        int base = sc[i] - hist[i];
        loc_base[i] = base;
        loc_cur[i]  = base;
        gb[i] = atomicAdd(&cursor[i * 16], hist[i]);
    }
    __syncthreads();
    for (int i = t; i < EPB; i += 256) {
        int e = e0 + i;
        int d = dst[e];
        int b = d >> 8;
        int p = atomicAdd(&loc_cur[b], 1);
        buf[p] = make_int2(src[e] | ((d & 255) << 17), __float_as_int(w[e]));
    }
    __syncthreads();
    for (int b = t; b < NBKT; b += 256) {
        int lb = loc_base[b], n = hist[b];
        int2* dstp = bucketbuf + (size_t)b * CAP + gb[b];
        for (int i = 0; i < n; ++i) dstp[i] = buf[lb + i];
    }
}

// ---------- scan of bucket counts -> bucket bases ----------
__global__ __launch_bounds__(512) void scanB_k(const int* __restrict__ cursor,
                                               int* __restrict__ bucketbase,
                                               int* __restrict__ row_start) {
    __shared__ int tmp[512];
    int t = threadIdx.x;
    int v = (t < NBKT) ? cursor[t * 16] : 0;
    tmp[t] = v;
    __syncthreads();
    for (int off = 1; off < 512; off <<= 1) {
        int add = (t >= off) ? tmp[t - off] : 0;
        __syncthreads(); tmp[t] += add; __syncthreads();
    }
    if (t < NBKT) bucketbase[t] = tmp[t] - v;
    if (t == 0) { bucketbase[NBKT] = NE; row_start[NN] = NE; }
}

// ---------- phase B: per-bucket CSR build + row_start + dinv ----------
__global__ __launch_bounds__(256) void phaseB_k(const int* __restrict__ bucketbase,
                                                const int2* __restrict__ bucketbuf,
                                                int2* __restrict__ e8,
                                                int* __restrict__ row_start,
                                                float* __restrict__ dinv) {
    __shared__ int2 buf[CAP];
    __shared__ int2 buf2[CAP];
    __shared__ int  hist2[256];
    __shared__ int  tmp[256];
    __shared__ int  base2[257];
    __shared__ int  cur2[256];
    const int b = blockIdx.x, t = threadIdx.x;
    const int g0   = bucketbase[b];
    const int cntb = bucketbase[b + 1] - g0;
    const int n0   = b * 256;
    const int nnb  = (NN - n0 < 256) ? (NN - n0) : 256;

    hist2[t] = 0;
    __syncthreads();
    const int2* bb = bucketbuf + (size_t)b * CAP;
    for (int i = t; i < cntb; i += 256) {
        int2 kv = bb[i];
        buf[i] = kv;
        atomicAdd(&hist2[kv.x >> 17], 1);
    }
    __syncthreads();
    int v = hist2[t];
    tmp[t] = v;
    __syncthreads();
    for (int off = 1; off < 256; off <<= 1) {
        int add = (t >= off) ? tmp[t - off] : 0;
        __syncthreads(); tmp[t] += add; __syncthreads();
    }
    int excl = tmp[t] - v;
    base2[t] = excl;
    cur2[t]  = excl;
    if (t == 0) base2[256] = cntb;
    if (t < nnb) row_start[n0 + t] = g0 + excl;
    __syncthreads();
    for (int i = t; i < cntb; i += 256) {
        int2 kv = buf[i];
        int d = kv.x >> 17;
        int p = atomicAdd(&cur2[d], 1);
        buf2[p] = make_int2(kv.x & 0x1FFFF, kv.y);
    }
    __syncthreads();
    for (int i = t; i < cntb; i += 256) e8[g0 + i] = buf2[i];
    if (t < nnb) {
        float s = 0.f;
        int j1 = base2[t + 1];
        for (int j = base2[t]; j < j1; ++j) s += __int_as_float(buf2[j].y);
        dinv[n0 + t] = rsqrtf(1.0f + s);
    }
}

// ---------- layer-1 GEMM via MFMA bf16, pre-scaled: h1'[r] = bf16(dinv[r] * (x@W1)[r]) ----------
__global__ __launch_bounds__(256) void gemm1_mfma_k(const float* __restrict__ x,
                                                    const short* __restrict__ w1t,  // bf16 [64][256]
                                                    const float* __restrict__ dinv,
                                                    unsigned short* __restrict__ h1) {
    const int wave = threadIdx.x >> 6;
    const int lane = threadIdx.x & 63;
    const int m    = lane & 15;
    const int quad = lane >> 4;
    const int r0   = blockIdx.x * 64 + wave * 16;
    const int row  = r0 + m;
    const int rcl  = (row < NN) ? row : (NN - 1);
    const float* xrow = x + (size_t)rcl * FIN + quad * 8;

    float4v acc0 = {0.f,0.f,0.f,0.f}, acc1 = acc0, acc2 = acc0, acc3 = acc0;

#pragma unroll
    for (int kc = 0; kc < 8; ++kc) {
        const int kof = kc * 32 + quad * 8;
        float4 xa = *(const float4*)(xrow + kc * 32);
        float4 xb = *(const float4*)(xrow + kc * 32 + 4);
        short8 a;
        a[0] = f2bf(xa.x); a[1] = f2bf(xa.y); a[2] = f2bf(xa.z); a[3] = f2bf(xa.w);
        a[4] = f2bf(xb.x); a[5] = f2bf(xb.y); a[6] = f2bf(xb.z); a[7] = f2bf(xb.w);
        short8 b0 = *(const short8*)(w1t + (0 * 16 + m) * FIN + kof);
        short8 b1 = *(const short8*)(w1t + (1 * 16 + m) * FIN + kof);
        short8 b2 = *(const short8*)(w1t + (2 * 16 + m) * FIN + kof);
        short8 b3 = *(const short8*)(w1t + (3 * 16 + m) * FIN + kof);
        acc0 = __builtin_amdgcn_mfma_f32_16x16x32_bf16(a, b0, acc0, 0, 0, 0);
        acc1 = __builtin_amdgcn_mfma_f32_16x16x32_bf16(a, b1, acc1, 0, 0, 0);
        acc2 = __builtin_amdgcn_mfma_f32_16x16x32_bf16(a, b2, acc2, 0, 0, 0);
        acc3 = __builtin_amdgcn_mfma_f32_16x16x32_bf16(a, b3, acc3, 0, 0, 0);
    }
    // C/D layout: col = lane&15, row = quad*4 + reg
#pragma unroll
    for (int r = 0; r < 4; ++r) {
        int rr = r0 + quad * 4 + r;
        if (rr < NN) {
            float dv = dinv[rr];
            unsigned short* hp = h1 + (size_t)rr * HID + m;
            hp[0]  = (unsigned short)f2bf(acc0[r] * dv);
            hp[16] = (unsigned short)f2bf(acc1[r] * dv);
            hp[32] = (unsigned short)f2bf(acc2[r] * dv);
            hp[48] = (unsigned short)f2bf(acc3[r] * dv);
        }
    }
}

// ---------- gatherA: agg1 = dv*(sum w*h1'[s]) + dv*h1'[v]; emit R' = bf16(dv*relu(agg1+b1)) ----------
__global__ __launch_bounds__(256) void gatherA_k(const int* __restrict__ row_start,
                                                 const int2* __restrict__ e8,
                                                 const float* __restrict__ dinv,
                                                 const unsigned short* __restrict__ h,
                                                 const float* __restrict__ b1,
                                                 unsigned short* __restrict__ Rp) {
    const int v = blockIdx.x * 4 + (threadIdx.x >> 6);
    const int lane = threadIdx.x & 63;
    const int i0 = row_start[v], i1 = row_start[v + 1];
    float acc0 = 0.f, acc1 = 0.f, acc2 = 0.f, acc3 = 0.f;
    int i = i0;
    for (; i + 4 <= i1; i += 4) {
        int2 a = e8[i + 0], b = e8[i + 1], c = e8[i + 2], d = e8[i + 3];
        acc0 = fmaf(bf2f(h[(size_t)a.x * HID + lane]), __int_as_float(a.y), acc0);
        acc1 = fmaf(bf2f(h[(size_t)b.x * HID + lane]), __int_as_float(b.y), acc1);
        acc2 = fmaf(bf2f(h[(size_t)c.x * HID + lane]), __int_as_float(c.y), acc2);
        acc3 = fmaf(bf2f(h[(size_t)d.x * HID + lane]), __int_as_float(d.y), acc3);
    }
    for (; i < i1; ++i) {
        int2 a = e8[i];
        acc0 = fmaf(bf2f(h[(size_t)a.x * HID + lane]), __int_as_float(a.y), acc0);
    }
    const float dv = dinv[v];
    float r = (acc0 + acc1) + (acc2 + acc3);
    r = dv * (r + bf2f(h[(size_t)v * HID + lane]));   // + self-loop (h' already has dinv[v])
    r = fmaxf(r + b1[lane], 0.f);                     // relu(agg1 + b1)
    Rp[(size_t)v * HID + lane] = (unsigned short)f2bf(dv * r);  // pre-scale for gatherB
}

// ---------- gatherB: agg2 = dv*(sum w*R'[s]) + dv*R'[v] ----------
__global__ __launch_bounds__(256) void gatherB_k(const int* __restrict__ row_start,
                                                 const int2* __restrict__ e8,
                                                 const float* __restrict__ dinv,
                                                 const unsigned short* __restrict__ Rp,
                                                 float* __restrict__ agg2) {
    const int v = blockIdx.x * 4 + (threadIdx.x >> 6);
    const int lane = threadIdx.x & 63;
    const int i0 = row_start[v], i1 = row_start[v + 1];
    float acc0 = 0.f, acc1 = 0.f, acc2 = 0.f, acc3 = 0.f;
    int i = i0;
    for (; i + 4 <= i1; i += 4) {
        int2 a = e8[i + 0], b = e8[i + 1], c = e8[i + 2], d = e8[i + 3];
        acc0 = fmaf(bf2f(Rp[(size_t)a.x * HID + lane]), __int_as_float(a.y), acc0);
        acc1 = fmaf(bf2f(Rp[(size_t)b.x * HID + lane]), __int_as_float(b.y), acc1);
        acc2 = fmaf(bf2f(Rp[(size_t)c.x * HID + lane]), __int_as_float(c.y), acc2);
        acc3 = fmaf(bf2f(Rp[(size_t)d.x * HID + lane]), __int_as_float(d.y), acc3);
    }
    for (; i < i1; ++i) {
        int2 a = e8[i];
        acc0 = fmaf(bf2f(Rp[(size_t)a.x * HID + lane]), __int_as_float(a.y), acc0);
    }
    const float dv = dinv[v];
    float r = (acc0 + acc1) + (acc2 + acc3);
    agg2[(size_t)v * HID + lane] = dv * (r + bf2f(Rp[(size_t)v * HID + lane]));
}

// ---------- gemm3 + log_softmax: out = logsm(agg2 @ W2 + b2), thread per node ----------
__global__ __launch_bounds__(256) void gemm3_logsm_k(const float* __restrict__ agg2,
                                                     const float* __restrict__ W2,
                                                     const float* __restrict__ b2,
                                                     float* __restrict__ out) {
    __shared__ float w2s[HID * NC];
    __shared__ float b2s[NC];
    for (int i = threadIdx.x; i < HID * NC; i += 256) w2s[i] = W2[i];
    if (threadIdx.x < NC) b2s[threadIdx.x] = b2[threadIdx.x];
    __syncthreads();

    const int r = blockIdx.x * 256 + threadIdx.x;
    if (r >= NN) return;
    float acc[NC];
#pragma unroll
    for (int c = 0; c < NC; ++c) acc[c] = b2s[c];

    const float4* row4 = (const float4*)(agg2 + (size_t)r * HID);
    for (int kk = 0; kk < HID; kk += 4) {
        float4 v = row4[kk >> 2];
#pragma unroll
        for (int c = 0; c < NC; ++c) {
            acc[c] = fmaf(v.x, w2s[(kk + 0) * NC + c], acc[c]);
            acc[c] = fmaf(v.y, w2s[(kk + 1) * NC + c], acc[c]);
            acc[c] = fmaf(v.z, w2s[(kk + 2) * NC + c], acc[c]);
            acc[c] = fmaf(v.w, w2s[(kk + 3) * NC + c], acc[c]);
        }
    }
    float m = acc[0];
#pragma unroll
    for (int c = 1; c < NC; ++c) m = fmaxf(m, acc[c]);
    float s = 0.f;
#pragma unroll
    for (int c = 0; c < NC; ++c) s += __expf(acc[c] - m);
    float lg = m + __logf(s);
    float* outp = out + (size_t)r * NC;
#pragma unroll
    for (int c = 0; c < NC; c += 4)
        *(float4*)&outp[c] = make_float4(acc[c] - lg, acc[c+1] - lg, acc[c+2] - lg, acc[c+3] - lg);
}

extern "C" void kernel_launch(void* const* d_in, const int* in_sizes, int n_in,
                              void* d_out, int out_size, void* d_ws, size_t ws_size,
                              hipStream_t stream) {
    const float* x  = (const float*)d_in[0];
    const int*   ei = (const int*)d_in[1];     // [2, E]: row0=src, row1=dst
    const float* ea = (const float*)d_in[2];
    const float* W1 = (const float*)d_in[3];
    const float* b1 = (const float*)d_in[4];
    const float* W2 = (const float*)d_in[5];
    const float* b2 = (const float*)d_in[6];
    const int* src = ei;
    const int* dst = ei + NE;
    float* out = (float*)d_out;

    char* ws = (char*)d_ws;
    float* dinv       = (float*)(ws + 0);            //    400,000 B
    int*   row_start  = (int*)  (ws + 400000);       //    400,016 B (NN+1)
    int*   cursor     = (int*)  (ws + 800016);       //     25,024 B (391*16, line-padded)
    int*   bucketbase = (int*)  (ws + 825040);       //      1,568 B
    int2*  e8         = (int2*) (ws + 826608);       // 12,800,000 B
    unsigned short* h1 = (unsigned short*)(ws + 13626608);   // 12,800,000 B (bf16, dinv-prescaled)
    unsigned short* Rp = (unsigned short*)(ws + 26426608);   // 12,800,000 B (bf16, dinv-prescaled)
    float* agg2       = (float*)(ws + 39226608);     // 25,600,000 B
    short* w1t        = (short*)(ws + 64826608);     //     32,768 B -> total 64.86 MB
    int2*  bucketbuf  = (int2*)agg2;                 // 14.4 MB, aliases agg2 (dead until gatherB)

    hipMemsetAsync(cursor, 0, 391 * 16 * sizeof(int), stream);

    w1cvt_k <<<64,   256, 0, stream>>>(W1, w1t);
    phaseA_k<<<256,  256, 0, stream>>>(src, dst, ea, cursor, bucketbuf);
    scanB_k <<<1,    512, 0, stream>>>(cursor, bucketbase, row_start);
    phaseB_k<<<NBKT, 256, 0, stream>>>(bucketbase, bucketbuf, e8, row_start, dinv);

    gemm1_mfma_k <<<(NN + 63) / 64, 256, 0, stream>>>(x, w1t, dinv, h1);
    gatherA_k    <<<NN / 4, 256, 0, stream>>>(row_start, e8, dinv, h1, b1, Rp);
    gatherB_k    <<<NN / 4, 256, 0, stream>>>(row_start, e8, dinv, Rp, agg2);
    gemm3_logsm_k<<<(NN + 255) / 256, 256, 0, stream>>>(agg2, W2, b2, out);
}